// Round 12
// baseline (1730.562 us; speedup 1.0000x reference)
//
#include <hip/hip_runtime.h>
#include <hip/hip_bf16.h>

#define MAXPH 0.78539816339744831f
#define NBN 512
#define NBF 256
typedef unsigned short ushort_t;

__device__ __forceinline__ float wsum64(float v) {
#pragma unroll
  for (int o = 32; o > 0; o >>= 1) v += __shfl_xor(v, o);
  return v;
}
__device__ __forceinline__ float bf2f(ushort_t u) {
  return __uint_as_float(((unsigned)u) << 16);
}

// ---- K1: zero AdjU/cnt + prep Wg1/C0G1
__global__ void k1_init(const float* __restrict__ ln_g, const float* __restrict__ ln_b,
                        const float* __restrict__ w1, const float* __restrict__ b1,
                        float* __restrict__ Wg1, float* __restrict__ C0G1,
                        unsigned* __restrict__ AdjU, unsigned* __restrict__ cnt, int nb) {
  int t = threadIdx.x;
  for (int i = t; i < 4096; i += 256) AdjU[i] = 0u;
  for (int i = t; i < nb; i += 256) cnt[i] = 0u;
  for (int idx = t; idx < 4096; idx += 256) {
    int j = idx >> 5;
    Wg1[idx] = ln_g[j] * w1[idx];
  }
  if (t < 32) {
    float c0 = b1[t], g1 = 0.f;
    for (int j = 0; j < 128; ++j) {
      float w = w1[j * 32 + t];
      c0 = fmaf(ln_b[j], w, c0);
      g1 = fmaf(ln_g[j], w, g1);
    }
    C0G1[t] = c0;
    C0G1[32 + t] = g1;
  }
}

// ---- K2 mega: blocks [0,NBN) node | [NBN,NBN+NBF) fill | last = gcn+expm
__global__ __launch_bounds__(1024) void k2_mega(
    const float* __restrict__ x, const float* __restrict__ Wr,
    const float* __restrict__ Wg1, const float* __restrict__ C0G1,
    const float* __restrict__ w2, const float* __restrict__ b2,
    ushort_t* __restrict__ R, __hip_bfloat16* __restrict__ Ad,
    const int* __restrict__ ei, const float* __restrict__ ew, int ne,
    unsigned* __restrict__ cnt, unsigned* __restrict__ AdjU,
    int2* __restrict__ eb, int cap,
    const float* __restrict__ g1w, const float* __restrict__ g1b,
    const float* __restrict__ g2w, const float* __restrict__ g2b,
    const float* __restrict__ aw1, const float* __restrict__ ab1,
    const float* __restrict__ aw2, const float* __restrict__ ab2,
    const float* __restrict__ aw3, const float* __restrict__ ab3,
    float* __restrict__ Bg, float* __restrict__ UrT, float* __restrict__ UiT,
    int n) {
  __shared__ float SH[8192];
  __shared__ float sdv[64], sts[64], sgp[64], sz1[64], sz2[64];
  const int tid = threadIdx.x;
  const int bid = blockIdx.x;

  if (bid < NBN) {
    // ================= node =================
    for (int i = tid; i < 4096; i += 1024) {
      SH[i] = Wr[i];
      SH[4096 + i] = Wg1[i];
    }
    __syncthreads();
    const int lane = tid & 63;
    const int k = lane & 31;
    const int half = lane >> 5;
    const float* wg = SH + 4096 + half * 2048;
    const int wid = (bid * 1024 + tid) >> 6;
    const int nw = (NBN * 1024) >> 6;
    for (int node = wid; node < n; node += nw) {
      const float xv = x[node * 64 + lane];
      float s1 = wsum64(xv);
      float s2 = wsum64(xv * xv);
      float mean = s1 * 0.015625f;
      float var = fmaf(-mean, mean, s2 * 0.015625f);
      float rstd = rsqrtf(var + 1e-5f);
      float xr = (xv - mean) * rstd;
      float hv = 0.f;
#pragma unroll
      for (int m = 0; m < 64; ++m) hv = fmaf(__shfl(xr, m), SH[m * 64 + lane], hv);
      float mag = sqrtf(fmaf(hv, hv, 1e-8f));
      float cm = fminf(mag, 10.f);
      float t1 = wsum64(cm);
      float t2 = wsum64(cm * cm);
      float acc = 0.f;
#pragma unroll
      for (int m = 0; m < 64; ++m) acc = fmaf(__shfl(cm, m), wg[m * 32 + k], acc);
      ushort_t* rn = R + (size_t)node * 128;
      __hip_bfloat16 hb = __float2bfloat16(hv);
      rn[lane] = *(ushort_t*)&hb;
      __hip_bfloat16 ab = __float2bfloat16(acc);
      if (half == 0) Ad[(size_t)node * 32 + k] = ab;
      else           rn[64 + k] = *(ushort_t*)&ab;
      if (lane == 0) {
        float* sp = (float*)(rn + 96);
        sp[0] = t1;
        sp[1] = t2;
      }
    }
  } else if (bid < NBN + NBF) {
    // ================= fill =================
    int t2 = (bid - NBN) * 1024 + tid;
    int st = NBF * 1024;
    for (int e2 = t2; e2 < ne; e2 += st) {
      int s = ei[e2];
      int d = ei[ne + e2];
      int b = d >> 5;
      unsigned p = atomicAdd(&cnt[b], 1u);
      if (p < (unsigned)cap)
        eb[(size_t)b * cap + p] = make_int2(s | ((d & 31) << 25), __float_as_int(ew[e2]));
    }
  } else {
    // ================= gcn + expm (single block) =================
    unsigned* au = (unsigned*)SH;
    for (int i = tid; i < 4096; i += 1024) au[i] = 0u;
    __syncthreads();
    for (int e2 = tid; e2 < ne; e2 += 1024) {
      int s = ei[e2];
      int d = ei[ne + e2];
      if ((unsigned)(s | d) < 64u) atomicAdd(&au[d * 64 + s], 1u);
    }
    __syncthreads();
    for (int i = tid; i < 4096; i += 1024) {
      unsigned u = au[i];
      SH[i] = (float)u;  // in-place u32->f32, slot-exclusive
    }
    __syncthreads();
    if (tid < 64) {
      float deg = 1.f;
      for (int s2 = 0; s2 < 64; ++s2) deg += SH[tid * 64 + s2];
      sdv[tid] = rsqrtf(deg);
    }
    __syncthreads();
    if (tid < 64) {
      float a = 0.f;
      for (int s2 = 0; s2 < 64; ++s2) a = fmaf(SH[tid * 64 + s2], sdv[s2], a);
      sts[tid] = a;
    }
    __syncthreads();
    float* h1 = SH + 4096;
    for (int idx = tid; idx < 4096; idx += 1024) {
      int d = idx >> 6, kk = idx & 63;
      h1[idx] = fmaxf(fmaf(g1w[kk], fmaf(sts[d], sdv[d], sdv[d] * sdv[d]), g1b[kk]), 0.f);
    }
    __syncthreads();
    const int i = tid >> 4, j0 = (tid & 15) << 2;
    float xw[4] = {0, 0, 0, 0};
    for (int m = 0; m < 64; ++m) {
      float hm = h1[i * 64 + m];
      const float* w = g2w + m * 64 + j0;
#pragma unroll
      for (int q = 0; q < 4; ++q) xw[q] = fmaf(hm, w[q], xw[q]);
    }
    __syncthreads();
#pragma unroll
    for (int q = 0; q < 4; ++q) h1[i * 64 + j0 + q] = xw[q];  // xw over h1
    __syncthreads();
    {
      float a[4] = {0, 0, 0, 0};
      for (int s2 = 0; s2 < 64; ++s2) {
        float w = SH[i * 64 + s2] * sdv[s2];
        const float* xr = h1 + s2 * 64 + j0;
#pragma unroll
        for (int q = 0; q < 4; ++q) a[q] = fmaf(w, xr[q], a[q]);
      }
      float di = sdv[i], sc = di * di;
      float h2[4];
#pragma unroll
      for (int q = 0; q < 4; ++q)
        h2[q] = fmaf(a[q], di, fmaf(sc, h1[i * 64 + j0 + q], g2b[j0 + q]));
      __syncthreads();
#pragma unroll
      for (int q = 0; q < 4; ++q) h1[i * 64 + j0 + q] = h2[q];
    }
    __syncthreads();
    if (tid < 64) {
      float a = 0.f;
      for (int d = 0; d < 64; ++d) a += h1[d * 64 + tid];
      sgp[tid] = a * 0.015625f;
    }
    __syncthreads();
    if (tid < 64) {
      float a = ab1[tid];
      for (int m = 0; m < 64; ++m) a = fmaf(sgp[m], aw1[m * 64 + tid], a);
      sz1[tid] = fmaxf(a, 0.f);
    }
    __syncthreads();
    if (tid < 64) {
      float a = ab2[tid];
      for (int m = 0; m < 64; ++m) a = fmaf(sz1[m], aw2[m * 64 + tid], a);
      sz2[tid] = fmaxf(a, 0.f);
    }
    __syncthreads();
    for (int p4 = 0; p4 < 4; ++p4) {
      int rc = tid + p4 * 1024;
      float a = ab3[rc];
      for (int m = 0; m < 64; ++m) a = fmaf(sz2[m], aw3[m * 4096 + rc], a);
      SH[rc] = tanhf(a);  // p over adj (dead)
    }
    __syncthreads();
    const float SCC = 0.0015625f;  // 0.1*0.5/32
    for (int idx = tid; idx < 4096; idx += 1024) {
      int r = idx >> 6, c = idx & 63;
      float pr = SH[r * 64 + c], pt = SH[c * 64 + r];
      Bg[idx] = (pr - pt) * SCC;
      Bg[4096 + idx] = (pr + pt) * SCC;
    }
    __syncthreads();
    // expm in LDS, in-place (read-all / barrier / write)
    float* Xr = SH;
    float* Xi = SH + 4096;
    for (int idx = tid; idx < 4096; idx += 1024) {
      int r = idx >> 6, c = idx & 63;
      Xr[idx] = (r == c ? 1.f : 0.f) + Bg[idx] * (1.f / 6.f);
      Xi[idx] = Bg[4096 + idx] * (1.f / 6.f);
    }
    __syncthreads();
    for (int kk = 5; kk >= 1; --kk) {
      float ar[4] = {0, 0, 0, 0}, ai[4] = {0, 0, 0, 0};
      const float* brr = Bg + i * 64;
      const float* bir = Bg + 4096 + i * 64;
      for (int m = 0; m < 64; ++m) {
        float br = brr[m], bi = bir[m];
#pragma unroll
        for (int q = 0; q < 4; ++q) {
          float xr = Xr[m * 64 + j0 + q], xi = Xi[m * 64 + j0 + q];
          ar[q] = fmaf(br, xr, fmaf(-bi, xi, ar[q]));
          ai[q] = fmaf(br, xi, fmaf(bi, xr, ai[q]));
        }
      }
      __syncthreads();
      float inv = 1.f / (float)kk;
#pragma unroll
      for (int q = 0; q < 4; ++q) {
        int c = j0 + q;
        Xr[i * 64 + c] = (i == c ? 1.f : 0.f) + ar[q] * inv;
        Xi[i * 64 + c] = ai[q] * inv;
      }
      __syncthreads();
    }
    for (int sq = 0; sq < 5; ++sq) {
      float ar[4] = {0, 0, 0, 0}, ai[4] = {0, 0, 0, 0};
      for (int m = 0; m < 64; ++m) {
        float br = Xr[i * 64 + m], bi = Xi[i * 64 + m];
#pragma unroll
        for (int q = 0; q < 4; ++q) {
          float xr = Xr[m * 64 + j0 + q], xi = Xi[m * 64 + j0 + q];
          ar[q] = fmaf(br, xr, fmaf(-bi, xi, ar[q]));
          ai[q] = fmaf(br, xi, fmaf(bi, xr, ai[q]));
        }
      }
      __syncthreads();
#pragma unroll
      for (int q = 0; q < 4; ++q) {
        Xr[i * 64 + j0 + q] = ar[q];
        Xi[i * 64 + j0 + q] = ai[q];
      }
      __syncthreads();
    }
    for (int idx = tid; idx < 4096; idx += 1024) {
      int a2 = idx >> 6, b2i = idx & 63;
      UrT[idx] = Xr[b2i * 64 + a2];
      UiT[idx] = Xi[b2i * 64 + a2];
    }
  }
}

// ---- K3 aggr: block owns 32 dst nodes; self-loop tile init; 8 waves
__global__ __launch_bounds__(512) void k3_aggr(
    const int2* __restrict__ eb, const unsigned* __restrict__ cnt, int cap,
    const ushort_t* __restrict__ R, const __hip_bfloat16* __restrict__ Ad,
    const float* __restrict__ C0G1, const float* __restrict__ w2,
    const float* __restrict__ b2,
    float* __restrict__ Cr, float* __restrict__ Sr, int n) {
  __shared__ float tCr[2048];
  __shared__ float tSr[2048];
  __shared__ float sAdf[32 * 33];
  __shared__ float2 sS12[32];
  __shared__ float sc0[32], sg1[32], sw2[32];
  const int tid = threadIdx.x;
  const int lo = blockIdx.x << 5;
  const int rows = min(32, n - lo);
  if (tid < 32) {
    sc0[tid] = C0G1[tid];
    sg1[tid] = C0G1[32 + tid];
    sw2[tid] = w2[tid];
  }
  for (int idx = tid; idx < rows * 32; idx += 512) {
    int r = idx >> 5, kk = idx & 31;
    sAdf[r * 33 + kk] = __bfloat162float(Ad[(size_t)(lo + r) * 32 + kk]);
  }
  for (int idx = tid; idx < rows; idx += 512)
    sS12[idx] = *(const float2*)(R + (size_t)(lo + idx) * 128 + 96);
  __syncthreads();
  const int lane = tid & 63;
  const int wave = tid >> 6;  // 8 waves
  const float b2r = b2[0];
  // self-loop tile init
  for (int r = wave; r < 32; r += 8) {
    if (r < rows) {
      const ushort_t* rn = R + (size_t)(lo + r) * 128;
      float2 sp = sS12[r];
      float meanE = sp.x * 0.015625f;
      float varE = fmaf(-meanE, meanE, sp.y * 0.015625f);
      float rstdE = rsqrtf(varE + 1e-5f);
      int k = lane & 31;
      float ask = bf2f(rn[64 + k]);
      float pre = fmaf(rstdE, fmaf(-meanE, sg1[k], sAdf[r * 33 + k] + ask), sc0[k]);
      float contrib = fmaxf(pre, 0.f) * sw2[k];
      float z = fmaf(wsum64(contrib), 0.5f, b2r);
      float coup = 1.f / (1.f + expf(-z));
      float ph = fminf(0.3f * coup, MAXPH);
      float sn, cs;
      sincosf(ph, &sn, &cs);
      float hv = bf2f(rn[lane]);
      tCr[(r << 6) + lane] = hv * cs;
      tSr[(r << 6) + lane] = hv * sn;
    }
  }
  __syncthreads();
  const unsigned nEdge = min(cnt[blockIdx.x], (unsigned)cap);
  const size_t base = (size_t)blockIdx.x * cap;
  for (unsigned i0 = (unsigned)wave << 6; i0 < nEdge; i0 += 512) {
    int cnt64 = (int)min(64u, nEdge - i0);
    int s = 0, dloc = 0;
    float sn = 0.f, cs = 0.f;
    if (lane < cnt64) {
      int2 rec = eb[base + i0 + lane];
      s = rec.x & 0x1FFFFFF;
      dloc = (rec.x >> 25) & 31;
      const ushort_t* rs = R + (size_t)s * 128;
      float2 ps = *(const float2*)(rs + 96);
      float2 pd = sS12[dloc];
      float meanE = (ps.x + pd.x) * 0.0078125f;
      float varE = fmaf(-meanE, meanE, (ps.y + pd.y) * 0.0078125f);
      float rstdE = rsqrtf(varE + 1e-5f);
      const uint4* asq = (const uint4*)(rs + 64);
      const float* adr = sAdf + dloc * 33;
      float z = b2r;
#pragma unroll
      for (int q = 0; q < 4; ++q) {
        uint4 ub = asq[q];
        unsigned bv[4] = {ub.x, ub.y, ub.z, ub.w};
#pragma unroll
        for (int p = 0; p < 4; ++p) {
          int k0 = q * 8 + p * 2;
          float b0 = __uint_as_float(bv[p] << 16);
          float b1 = __uint_as_float(bv[p] & 0xFFFF0000u);
          float pre0 = fmaf(rstdE, fmaf(-meanE, sg1[k0], adr[k0] + b0), sc0[k0]);
          float pre1 = fmaf(rstdE, fmaf(-meanE, sg1[k0 + 1], adr[k0 + 1] + b1), sc0[k0 + 1]);
          z = fmaf(fmaxf(pre0, 0.f), sw2[k0], z);
          z = fmaf(fmaxf(pre1, 0.f), sw2[k0 + 1], z);
        }
      }
      float coup = 1.f / (1.f + expf(-z));
      float cw = fminf(fmaxf(__int_as_float(rec.y), 0.1f), 2.f);
      float ph = fminf(0.3f * coup * cw, MAXPH);
      sincosf(ph, &sn, &cs);
    }
    for (int j = 0; j < cnt64; j += 8) {
      int m = cnt64 - j;
      if (m > 8) m = 8;
      float hv[8], c8[8], n8[8];
      int dl[8];
#pragma unroll
      for (int kq = 0; kq < 8; ++kq) {
        int jj = j + (kq < m ? kq : m - 1);
        int sk = __shfl(s, jj);
        dl[kq] = __shfl(dloc, jj);
        c8[kq] = __shfl(cs, jj);
        n8[kq] = __shfl(sn, jj);
        hv[kq] = bf2f(R[(size_t)sk * 128 + lane]);
      }
#pragma unroll
      for (int kq = 0; kq < 8; ++kq) {
        if (kq < m) {
          atomicAdd(&tCr[(dl[kq] << 6) + lane], hv[kq] * c8[kq]);
          atomicAdd(&tSr[(dl[kq] << 6) + lane], hv[kq] * n8[kq]);
        }
      }
    }
  }
  __syncthreads();
  for (int idx = tid; idx < 2048; idx += 512) {
    int r = idx >> 6;
    if (r < rows) {
      Cr[(size_t)(lo + r) * 64 + (idx & 63)] = tCr[idx];
      Sr[(size_t)(lo + r) * 64 + (idx & 63)] = tSr[idx];
    }
  }
}

// ---- K4 final: aggr = [Cr,Sr] x U^T (complex), out = 0.5*aggr + 0.5*LN(x)
__global__ void k4_final(const float* __restrict__ x, const float* __restrict__ Cr,
                         const float* __restrict__ Sr, const float* __restrict__ UrT,
                         const float* __restrict__ UiT, float* __restrict__ out, int n) {
  __shared__ float sUr[4096], sUi[4096];
  for (int i = threadIdx.x; i < 4096; i += blockDim.x) {
    sUr[i] = UrT[i];
    sUi[i] = UiT[i];
  }
  __syncthreads();
  const int lane = threadIdx.x & 63;
  const int wid = (blockIdx.x * blockDim.x + threadIdx.x) >> 6;
  const int nw = (gridDim.x * blockDim.x) >> 6;
  const size_t imag_off = (size_t)n * 64;
  for (int node = wid; node < n; node += nw) {
    float cr = Cr[node * 64 + lane];
    float sr = Sr[node * 64 + lane];
    float ar = 0.f, ai = 0.f;
#pragma unroll
    for (int m = 0; m < 64; ++m) {
      float crm = __shfl(cr, m), srm = __shfl(sr, m);
      float ur = sUr[m * 64 + lane], ui = sUi[m * 64 + lane];
      ar = fmaf(crm, ur, fmaf(-srm, ui, ar));
      ai = fmaf(crm, ui, fmaf(srm, ur, ai));
    }
    float xv = x[node * 64 + lane];
    float s1 = wsum64(xv);
    float s2 = wsum64(xv * xv);
    float mean = s1 * 0.015625f;
    float var = fmaf(-mean, mean, s2 * 0.015625f);
    float xr = (xv - mean) * rsqrtf(var + 1e-5f);
    out[node * 64 + lane] = 0.5f * (ar + xr);
    out[imag_off + node * 64 + lane] = 0.5f * ai;
  }
}

extern "C" void kernel_launch(void* const* d_in, const int* in_sizes, int n_in,
                              void* d_out, int out_size, void* d_ws, size_t ws_size,
                              hipStream_t stream) {
  const float* x    = (const float*)d_in[0];
  const int*   ei   = (const int*)d_in[1];
  const float* ew   = (const float*)d_in[2];
  const float* Wr   = (const float*)d_in[3];
  const float* ln_g = (const float*)d_in[5];
  const float* ln_b = (const float*)d_in[6];
  const float* w1   = (const float*)d_in[7];
  const float* b1   = (const float*)d_in[8];
  const float* w2   = (const float*)d_in[9];
  const float* b2   = (const float*)d_in[10];
  const float* g1w  = (const float*)d_in[11];
  const float* g1b  = (const float*)d_in[12];
  const float* g2w  = (const float*)d_in[13];
  const float* g2b  = (const float*)d_in[14];
  const float* aw1  = (const float*)d_in[15];
  const float* ab1  = (const float*)d_in[16];
  const float* aw2  = (const float*)d_in[17];
  const float* ab2  = (const float*)d_in[18];
  const float* aw3  = (const float*)d_in[19];
  const float* ab3  = (const float*)d_in[20];
  const int n = in_sizes[0] / 64;
  const int e = in_sizes[1] / 2;
  const int nb = (n + 31) >> 5;
  const int cap = ((e + nb - 1) / nb) * 5 / 4 + 40;
  float* out = (float*)d_out;

  float* ws = (float*)d_ws;
  float* Wg1  = ws;                           // 4096
  float* C0G1 = ws + 4096;                    // 64
  float* UrT  = ws + 4160;                    // 4096
  float* UiT  = ws + 8256;                    // 4096
  float* Bg   = ws + 12352;                   // 8192
  unsigned* AdjU = (unsigned*)(ws + 20544);   // 4096 u32
  unsigned* cnt  = AdjU + 4096;               // nb u32
  size_t ebofs = (20544 + 4096 + (size_t)nb + 63) & ~(size_t)63;
  int2* eb = (int2*)(ws + ebofs);             // nb*cap int2
  size_t bigofs = (ebofs + 2 * (size_t)nb * cap + 63) & ~(size_t)63;
  float* big = ws + bigofs;
  float* Cr = big;                                     // 64n f32
  float* Sr = big + (size_t)64 * n;                    // 64n f32
  ushort_t* R = (ushort_t*)(big + (size_t)128 * n);    // n*128 ushort
  __hip_bfloat16* Ad = (__hip_bfloat16*)(big + (size_t)192 * n);  // 32n bf16

  k1_init<<<1, 256, 0, stream>>>(ln_g, ln_b, w1, b1, Wg1, C0G1, AdjU, cnt, nb);
  k2_mega<<<NBN + NBF + 1, 1024, 0, stream>>>(
      x, Wr, Wg1, C0G1, w2, b2, R, Ad, ei, ew, e, cnt, AdjU, eb, cap,
      g1w, g1b, g2w, g2b, aw1, ab1, aw2, ab2, aw3, ab3, Bg, UrT, UiT, n);
  k3_aggr<<<nb, 512, 0, stream>>>(eb, cnt, cap, R, Ad, C0G1, w2, b2, Cr, Sr, n);
  k4_final<<<1024, 256, 0, stream>>>(x, Cr, Sr, UrT, UiT, out, n);
}

// Round 13
// 1240.837 us; speedup vs baseline: 1.3947x; 1.3947x over previous
//
#include <hip/hip_runtime.h>
#include <hip/hip_bf16.h>
#include <hip/hip_fp16.h>

#define MAXPH 0.78539816339744831f
typedef unsigned short ushort_t;

__device__ __forceinline__ float wsum64(float v) {
#pragma unroll
  for (int o = 32; o > 0; o >>= 1) v += __shfl_xor(v, o);
  return v;
}
__device__ __forceinline__ float bf2f(ushort_t u) {
  return __uint_as_float(((unsigned)u) << 16);
}

// ---- kInit: zero cnt/cur; last block also preps Wg1/C0G1
__global__ void kInit(unsigned* __restrict__ cnt, unsigned* __restrict__ cur, int n,
                      const float* __restrict__ ln_g, const float* __restrict__ ln_b,
                      const float* __restrict__ w1, const float* __restrict__ b1,
                      float* __restrict__ Wg1, float* __restrict__ C0G1) {
  int t = blockIdx.x * blockDim.x + threadIdx.x;
  int st = gridDim.x * blockDim.x;
  for (int i = t; i < n; i += st) {
    cnt[i] = 0u;
    cur[i] = 0u;
  }
  if (blockIdx.x == gridDim.x - 1) {
    int tt = threadIdx.x;
    for (int idx = tt; idx < 4096; idx += 256) {
      int j = idx >> 5;
      Wg1[idx] = ln_g[j] * w1[idx];
    }
    if (tt < 32) {
      float c0 = b1[tt], g1 = 0.f;
      for (int j = 0; j < 128; ++j) {
        float w = w1[j * 32 + tt];
        c0 = fmaf(ln_b[j], w, c0);
        g1 = fmaf(ln_g[j], w, g1);
      }
      C0G1[tt] = c0;
      C0G1[32 + tt] = g1;
    }
  }
}

// ---- kCount: per-dst-node histogram
__global__ void kCount(const int* __restrict__ ei, int ne, unsigned* __restrict__ cnt) {
  int t = blockIdx.x * blockDim.x + threadIdx.x;
  int st = gridDim.x * blockDim.x;
  for (int e = t; e < ne; e += st) atomicAdd(&cnt[ei[ne + e]], 1u);
}

// ---- kScan: exclusive prefix over n counters (single block, 2-level)
__global__ __launch_bounds__(1024) void kScan(const unsigned* __restrict__ cnt,
                                              unsigned* __restrict__ off, int n) {
  __shared__ unsigned wsum[16];
  const int t = threadIdx.x;
  const int C = (n + 1023) >> 10;
  const int lo = t * C;
  const int hi = min(lo + C, n);
  unsigned s = 0;
  for (int i = lo; i < hi; ++i) s += cnt[i];
  unsigned v = s;
#pragma unroll
  for (int o = 1; o < 64; o <<= 1) {
    unsigned u = __shfl_up(v, o);
    if ((t & 63) >= o) v += u;
  }
  if ((t & 63) == 63) wsum[t >> 6] = v;
  __syncthreads();
  if (t == 0) {
    unsigned a = 0;
    for (int i = 0; i < 16; ++i) {
      unsigned c = wsum[i];
      wsum[i] = a;
      a += c;
    }
  }
  __syncthreads();
  unsigned run = wsum[t >> 6] + (v - s);
  for (int i = lo; i < hi; ++i) {
    off[i] = run;
    run += cnt[i];
  }
  if (t == 1023) off[n] = run;
}

// ---- kNode: LN -> h -> mag -> record {h bf16[64], As bf16[32], S12 f32[2]}; Ad; self-loop -> Crh/Srh
__global__ void kNode(const float* __restrict__ x, const float* __restrict__ Wr,
                      const float* __restrict__ Wg1, const float* __restrict__ C0G1,
                      const float* __restrict__ w2, const float* __restrict__ b2,
                      ushort_t* __restrict__ R, __hip_bfloat16* __restrict__ Ad,
                      __half* __restrict__ Crh, __half* __restrict__ Srh, int n) {
  __shared__ float sWr[4096];
  __shared__ float sWg1[4096];
  for (int i = threadIdx.x; i < 4096; i += blockDim.x) {
    sWr[i] = Wr[i];
    sWg1[i] = Wg1[i];
  }
  __syncthreads();
  const int lane = threadIdx.x & 63;
  const int k = lane & 31;
  const int half = lane >> 5;
  const float c0r = C0G1[k], g1r = C0G1[32 + k], w2r = w2[k], b2r = b2[0];
  const float* wg = sWg1 + half * 2048;
  const int wid = (blockIdx.x * blockDim.x + threadIdx.x) >> 6;
  const int nw = (gridDim.x * blockDim.x) >> 6;
  for (int node = wid; node < n; node += nw) {
    const float xv = x[node * 64 + lane];
    float s1 = wsum64(xv);
    float s2 = wsum64(xv * xv);
    float mean = s1 * 0.015625f;
    float var = fmaf(-mean, mean, s2 * 0.015625f);
    float rstd = rsqrtf(var + 1e-5f);
    float xr = (xv - mean) * rstd;
    float hv = 0.f;
#pragma unroll
    for (int m = 0; m < 64; ++m) hv = fmaf(__shfl(xr, m), sWr[m * 64 + lane], hv);
    float mag = sqrtf(fmaf(hv, hv, 1e-8f));
    float cm = fminf(mag, 10.f);
    float t1 = wsum64(cm);
    float t2 = wsum64(cm * cm);
    float acc = 0.f;
#pragma unroll
    for (int m = 0; m < 64; ++m) acc = fmaf(__shfl(cm, m), wg[m * 32 + k], acc);
    ushort_t* rn = R + (size_t)node * 128;
    __hip_bfloat16 hb = __float2bfloat16(hv);
    rn[lane] = *(ushort_t*)&hb;
    __hip_bfloat16 ab = __float2bfloat16(acc);
    if (half == 0) Ad[(size_t)node * 32 + k] = ab;
    else           rn[64 + k] = *(ushort_t*)&ab;
    if (lane == 0) {
      float* sp = (float*)(rn + 96);
      sp[0] = t1;
      sp[1] = t2;
    }
    // self-loop (i,i), ew=1 -> clip=1
    float meanE = t1 * 0.015625f;
    float varE = fmaf(-meanE, meanE, t2 * 0.015625f);
    float rstdE = rsqrtf(varE + 1e-5f);
    float hsum = acc + __shfl_xor(acc, 32);
    float pre = fmaf(rstdE, fmaf(-meanE, g1r, hsum), c0r);
    float contrib = fmaxf(pre, 0.f) * w2r;
    float z = fmaf(wsum64(contrib), 0.5f, b2r);
    float coup = 1.f / (1.f + expf(-z));
    float ph = fminf(0.3f * coup, MAXPH);
    float sn, cs;
    sincosf(ph, &sn, &cs);
    Crh[(size_t)node * 64 + lane] = __float2half(hv * cs);
    Srh[(size_t)node * 64 + lane] = __float2half(hv * sn);
  }
}

// ---- kPhaseFill: lane-per-edge phase compute, write {s,cos,sin} to dst-sorted slot
__global__ void kPhaseFill(const int* __restrict__ ei, const float* __restrict__ ew, int ne,
                           const ushort_t* __restrict__ R, const __hip_bfloat16* __restrict__ Ad,
                           const float* __restrict__ C0G1, const float* __restrict__ w2,
                           const float* __restrict__ b2,
                           const unsigned* __restrict__ off, unsigned* __restrict__ cur,
                           int* __restrict__ recS, float2* __restrict__ recCS) {
  const float b2r = b2[0];
  int t = blockIdx.x * blockDim.x + threadIdx.x;
  int st = gridDim.x * blockDim.x;
  for (int e = t; e < ne; e += st) {
    int s = ei[e];
    int d = ei[ne + e];
    const ushort_t* rs = R + (size_t)s * 128;
    const ushort_t* rd = R + (size_t)d * 128;
    float2 ps = *(const float2*)(rs + 96);
    float2 pd = *(const float2*)(rd + 96);
    float meanE = (ps.x + pd.x) * 0.0078125f;
    float varE = fmaf(-meanE, meanE, (ps.y + pd.y) * 0.0078125f);
    float rstdE = rsqrtf(varE + 1e-5f);
    const uint4* asq = (const uint4*)(rs + 64);
    const uint4* adq = (const uint4*)(Ad + (size_t)d * 32);
    float z = b2r;
#pragma unroll
    for (int q = 0; q < 4; ++q) {
      uint4 ua = adq[q];
      uint4 ub = asq[q];
      unsigned av[4] = {ua.x, ua.y, ua.z, ua.w};
      unsigned bv[4] = {ub.x, ub.y, ub.z, ub.w};
#pragma unroll
      for (int p = 0; p < 4; ++p) {
        int k0 = q * 8 + p * 2;
        float a0 = __uint_as_float(av[p] << 16);
        float a1 = __uint_as_float(av[p] & 0xFFFF0000u);
        float b0 = __uint_as_float(bv[p] << 16);
        float b1 = __uint_as_float(bv[p] & 0xFFFF0000u);
        float pre0 = fmaf(rstdE, fmaf(-meanE, C0G1[32 + k0], a0 + b0), C0G1[k0]);
        float pre1 = fmaf(rstdE, fmaf(-meanE, C0G1[32 + k0 + 1], a1 + b1), C0G1[k0 + 1]);
        z = fmaf(fmaxf(pre0, 0.f), w2[k0], z);
        z = fmaf(fmaxf(pre1, 0.f), w2[k0 + 1], z);
      }
    }
    float coup = 1.f / (1.f + expf(-z));
    float cw = fminf(fmaxf(ew[e], 0.1f), 2.f);
    float ph = fminf(0.3f * coup * cw, MAXPH);
    float sn, cs;
    sincosf(ph, &sn, &cs);
    unsigned p = atomicAdd(&cur[d], 1u);
    unsigned pos = off[d] + p;
    recS[pos] = s;
    recCS[pos] = make_float2(cs, sn);
  }
}

// ---- kScatter: wave-per-node register-accumulate gather; no shfl, no atomics
__global__ __launch_bounds__(256) void kScatter(
    const unsigned* __restrict__ off, const int* __restrict__ recS,
    const float2* __restrict__ recCS, const ushort_t* __restrict__ R,
    __half* __restrict__ Crh, __half* __restrict__ Srh, int n) {
  const int lane = threadIdx.x & 63;
  const int wid = (blockIdx.x * blockDim.x + threadIdx.x) >> 6;
  const int nw = (gridDim.x * blockDim.x) >> 6;
  for (int d = wid; d < n; d += nw) {
    unsigned u0 = off[d], u1 = off[d + 1];
    float accR = 0.f, accI = 0.f;
    unsigned j = u0;
    for (; j + 8 <= u1; j += 8) {
      int s8[8];
      float2 c8[8];
#pragma unroll
      for (int k = 0; k < 8; ++k) {
        s8[k] = recS[j + k];
        c8[k] = recCS[j + k];
      }
#pragma unroll
      for (int k = 0; k < 8; ++k) {
        float hv = bf2f(R[(size_t)s8[k] * 128 + lane]);
        accR = fmaf(hv, c8[k].x, accR);
        accI = fmaf(hv, c8[k].y, accI);
      }
    }
    for (; j < u1; ++j) {
      int s = recS[j];
      float2 c = recCS[j];
      float hv = bf2f(R[(size_t)s * 128 + lane]);
      accR = fmaf(hv, c.x, accR);
      accI = fmaf(hv, c.y, accI);
    }
    size_t idx = (size_t)d * 64 + lane;
    Crh[idx] = __float2half(__half2float(Crh[idx]) + accR);
    Srh[idx] = __float2half(__half2float(Srh[idx]) + accI);
  }
}

// ---- kGcnExpm: single block — Adj histogram + GCN x2 + pool + MLP + expm -> U^T
__global__ __launch_bounds__(1024) void kGcnExpm(
    const int* __restrict__ ei, int ne,
    const float* __restrict__ g1w, const float* __restrict__ g1b,
    const float* __restrict__ g2w, const float* __restrict__ g2b,
    const float* __restrict__ aw1, const float* __restrict__ ab1,
    const float* __restrict__ aw2, const float* __restrict__ ab2,
    const float* __restrict__ aw3, const float* __restrict__ ab3,
    float* __restrict__ Bg, float* __restrict__ UrT, float* __restrict__ UiT) {
  __shared__ float SH[8192];
  __shared__ float sdv[64], sts[64], sgp[64], sz1[64], sz2[64];
  const int tid = threadIdx.x;
  unsigned* au = (unsigned*)SH;
  for (int i = tid; i < 4096; i += 1024) au[i] = 0u;
  __syncthreads();
  for (int e2 = tid; e2 < ne; e2 += 1024) {
    int s = ei[e2];
    int d = ei[ne + e2];
    if ((unsigned)(s | d) < 64u) atomicAdd(&au[d * 64 + s], 1u);
  }
  __syncthreads();
  for (int i = tid; i < 4096; i += 1024) SH[i] = (float)au[i];
  __syncthreads();
  if (tid < 64) {
    float deg = 1.f;
    for (int s2 = 0; s2 < 64; ++s2) deg += SH[tid * 64 + s2];
    sdv[tid] = rsqrtf(deg);
  }
  __syncthreads();
  if (tid < 64) {
    float a = 0.f;
    for (int s2 = 0; s2 < 64; ++s2) a = fmaf(SH[tid * 64 + s2], sdv[s2], a);
    sts[tid] = a;
  }
  __syncthreads();
  float* h1 = SH + 4096;
  for (int idx = tid; idx < 4096; idx += 1024) {
    int d = idx >> 6, kk = idx & 63;
    h1[idx] = fmaxf(fmaf(g1w[kk], fmaf(sts[d], sdv[d], sdv[d] * sdv[d]), g1b[kk]), 0.f);
  }
  __syncthreads();
  const int i = tid >> 4, j0 = (tid & 15) << 2;
  float xw[4] = {0, 0, 0, 0};
  for (int m = 0; m < 64; ++m) {
    float hm = h1[i * 64 + m];
    const float* w = g2w + m * 64 + j0;
#pragma unroll
    for (int q = 0; q < 4; ++q) xw[q] = fmaf(hm, w[q], xw[q]);
  }
  __syncthreads();
#pragma unroll
  for (int q = 0; q < 4; ++q) h1[i * 64 + j0 + q] = xw[q];
  __syncthreads();
  {
    float a[4] = {0, 0, 0, 0};
    for (int s2 = 0; s2 < 64; ++s2) {
      float w = SH[i * 64 + s2] * sdv[s2];
      const float* xr = h1 + s2 * 64 + j0;
#pragma unroll
      for (int q = 0; q < 4; ++q) a[q] = fmaf(w, xr[q], a[q]);
    }
    float di = sdv[i], sc = di * di;
    float h2[4];
#pragma unroll
    for (int q = 0; q < 4; ++q)
      h2[q] = fmaf(a[q], di, fmaf(sc, h1[i * 64 + j0 + q], g2b[j0 + q]));
    __syncthreads();
#pragma unroll
    for (int q = 0; q < 4; ++q) h1[i * 64 + j0 + q] = h2[q];
  }
  __syncthreads();
  if (tid < 64) {
    float a = 0.f;
    for (int d = 0; d < 64; ++d) a += h1[d * 64 + tid];
    sgp[tid] = a * 0.015625f;
  }
  __syncthreads();
  if (tid < 64) {
    float a = ab1[tid];
    for (int m = 0; m < 64; ++m) a = fmaf(sgp[m], aw1[m * 64 + tid], a);
    sz1[tid] = fmaxf(a, 0.f);
  }
  __syncthreads();
  if (tid < 64) {
    float a = ab2[tid];
    for (int m = 0; m < 64; ++m) a = fmaf(sz1[m], aw2[m * 64 + tid], a);
    sz2[tid] = fmaxf(a, 0.f);
  }
  __syncthreads();
  for (int p4 = 0; p4 < 4; ++p4) {
    int rc = tid + p4 * 1024;
    float a = ab3[rc];
    for (int m = 0; m < 64; ++m) a = fmaf(sz2[m], aw3[m * 4096 + rc], a);
    SH[rc] = tanhf(a);
  }
  __syncthreads();
  const float SCC = 0.0015625f;  // 0.1*0.5/32
  for (int idx = tid; idx < 4096; idx += 1024) {
    int r = idx >> 6, c = idx & 63;
    float pr = SH[r * 64 + c], pt = SH[c * 64 + r];
    Bg[idx] = (pr - pt) * SCC;
    Bg[4096 + idx] = (pr + pt) * SCC;
  }
  __syncthreads();
  float* Xr = SH;
  float* Xi = SH + 4096;
  for (int idx = tid; idx < 4096; idx += 1024) {
    int r = idx >> 6, c = idx & 63;
    Xr[idx] = (r == c ? 1.f : 0.f) + Bg[idx] * (1.f / 6.f);
    Xi[idx] = Bg[4096 + idx] * (1.f / 6.f);
  }
  __syncthreads();
  for (int kk = 5; kk >= 1; --kk) {
    float ar[4] = {0, 0, 0, 0}, ai[4] = {0, 0, 0, 0};
    const float* brr = Bg + i * 64;
    const float* bir = Bg + 4096 + i * 64;
    for (int m = 0; m < 64; ++m) {
      float br = brr[m], bi = bir[m];
#pragma unroll
      for (int q = 0; q < 4; ++q) {
        float xr = Xr[m * 64 + j0 + q], xi = Xi[m * 64 + j0 + q];
        ar[q] = fmaf(br, xr, fmaf(-bi, xi, ar[q]));
        ai[q] = fmaf(br, xi, fmaf(bi, xr, ai[q]));
      }
    }
    __syncthreads();
    float inv = 1.f / (float)kk;
#pragma unroll
    for (int q = 0; q < 4; ++q) {
      int c = j0 + q;
      Xr[i * 64 + c] = (i == c ? 1.f : 0.f) + ar[q] * inv;
      Xi[i * 64 + c] = ai[q] * inv;
    }
    __syncthreads();
  }
  for (int sq = 0; sq < 5; ++sq) {
    float ar[4] = {0, 0, 0, 0}, ai[4] = {0, 0, 0, 0};
    for (int m = 0; m < 64; ++m) {
      float br = Xr[i * 64 + m], bi = Xi[i * 64 + m];
#pragma unroll
      for (int q = 0; q < 4; ++q) {
        float xr = Xr[m * 64 + j0 + q], xi = Xi[m * 64 + j0 + q];
        ar[q] = fmaf(br, xr, fmaf(-bi, xi, ar[q]));
        ai[q] = fmaf(br, xi, fmaf(bi, xr, ai[q]));
      }
    }
    __syncthreads();
#pragma unroll
    for (int q = 0; q < 4; ++q) {
      Xr[i * 64 + j0 + q] = ar[q];
      Xi[i * 64 + j0 + q] = ai[q];
    }
    __syncthreads();
  }
  for (int idx = tid; idx < 4096; idx += 1024) {
    int a2 = idx >> 6, b2i = idx & 63;
    UrT[idx] = Xr[b2i * 64 + a2];
    UiT[idx] = Xi[b2i * 64 + a2];
  }
}

// ---- kFinal: aggr = [Cr,Sr] x U^T (complex), out = 0.5*aggr + 0.5*LN(x)
__global__ void kFinal(const float* __restrict__ x, const __half* __restrict__ Crh,
                       const __half* __restrict__ Srh, const float* __restrict__ UrT,
                       const float* __restrict__ UiT, float* __restrict__ out, int n) {
  __shared__ float sUr[4096], sUi[4096];
  for (int i = threadIdx.x; i < 4096; i += blockDim.x) {
    sUr[i] = UrT[i];
    sUi[i] = UiT[i];
  }
  __syncthreads();
  const int lane = threadIdx.x & 63;
  const int wid = (blockIdx.x * blockDim.x + threadIdx.x) >> 6;
  const int nw = (gridDim.x * blockDim.x) >> 6;
  const size_t imag_off = (size_t)n * 64;
  for (int node = wid; node < n; node += nw) {
    float cr = __half2float(Crh[(size_t)node * 64 + lane]);
    float sr = __half2float(Srh[(size_t)node * 64 + lane]);
    float ar = 0.f, ai = 0.f;
#pragma unroll
    for (int m = 0; m < 64; ++m) {
      float crm = __shfl(cr, m), srm = __shfl(sr, m);
      float ur = sUr[m * 64 + lane], ui = sUi[m * 64 + lane];
      ar = fmaf(crm, ur, fmaf(-srm, ui, ar));
      ai = fmaf(crm, ui, fmaf(srm, ur, ai));
    }
    float xv = x[node * 64 + lane];
    float s1 = wsum64(xv);
    float s2 = wsum64(xv * xv);
    float mean = s1 * 0.015625f;
    float var = fmaf(-mean, mean, s2 * 0.015625f);
    float xr = (xv - mean) * rsqrtf(var + 1e-5f);
    out[node * 64 + lane] = 0.5f * (ar + xr);
    out[imag_off + node * 64 + lane] = 0.5f * ai;
  }
}

extern "C" void kernel_launch(void* const* d_in, const int* in_sizes, int n_in,
                              void* d_out, int out_size, void* d_ws, size_t ws_size,
                              hipStream_t stream) {
  const float* x    = (const float*)d_in[0];
  const int*   ei   = (const int*)d_in[1];
  const float* ew   = (const float*)d_in[2];
  const float* Wr   = (const float*)d_in[3];
  const float* ln_g = (const float*)d_in[5];
  const float* ln_b = (const float*)d_in[6];
  const float* w1   = (const float*)d_in[7];
  const float* b1   = (const float*)d_in[8];
  const float* w2   = (const float*)d_in[9];
  const float* b2   = (const float*)d_in[10];
  const float* g1w  = (const float*)d_in[11];
  const float* g1b  = (const float*)d_in[12];
  const float* g2w  = (const float*)d_in[13];
  const float* g2b  = (const float*)d_in[14];
  const float* aw1  = (const float*)d_in[15];
  const float* ab1  = (const float*)d_in[16];
  const float* aw2  = (const float*)d_in[17];
  const float* ab2  = (const float*)d_in[18];
  const float* aw3  = (const float*)d_in[19];
  const float* ab3  = (const float*)d_in[20];
  const int n = in_sizes[0] / 64;
  const int e = in_sizes[1] / 2;
  float* out = (float*)d_out;

  float* ws = (float*)d_ws;
  float* Wg1  = ws;                           // 4096
  float* C0G1 = ws + 4096;                    // 64
  float* UrT  = ws + 4160;                    // 4096
  float* UiT  = ws + 8256;                    // 4096
  float* Bg   = ws + 12352;                   // 8192  -> ends 20544
  unsigned* cnt = (unsigned*)(ws + 20544);    // n
  unsigned* off = cnt + n;                    // n+1
  unsigned* cur = off + n + 1;                // n
  size_t p0 = (20544 + 3 * (size_t)n + 1 + 63) & ~(size_t)63;
  int* recS = (int*)(ws + p0);                // e
  size_t p1 = (p0 + (size_t)e + 1) & ~(size_t)1;
  float2* recCS = (float2*)(ws + p1);         // 2e
  size_t p2 = p1 + 2 * (size_t)e;
  ushort_t* R = (ushort_t*)(ws + p2);         // 64n f32-units
  size_t p3 = p2 + 64 * (size_t)n;
  __hip_bfloat16* Ad = (__hip_bfloat16*)(ws + p3);  // 16n
  size_t p4 = p3 + 16 * (size_t)n;
  __half* Crh = (__half*)(ws + p4);           // 32n
  __half* Srh = (__half*)(ws + p4 + 32 * (size_t)n);  // 32n

  kInit<<<512, 256, 0, stream>>>(cnt, cur, n, ln_g, ln_b, w1, b1, Wg1, C0G1);
  kNode<<<1024, 256, 0, stream>>>(x, Wr, Wg1, C0G1, w2, b2, R, Ad, Crh, Srh, n);
  kCount<<<1024, 256, 0, stream>>>(ei, e, cnt);
  kScan<<<1, 1024, 0, stream>>>(cnt, off, n);
  kPhaseFill<<<1024, 256, 0, stream>>>(ei, ew, e, R, Ad, C0G1, w2, b2, off, cur, recS, recCS);
  kScatter<<<2048, 256, 0, stream>>>(off, recS, recCS, R, Crh, Srh, n);
  kGcnExpm<<<1, 1024, 0, stream>>>(ei, e, g1w, g1b, g2w, g2b, aw1, ab1, aw2, ab2, aw3, ab3,
                                   Bg, UrT, UiT);
  kFinal<<<1024, 256, 0, stream>>>(x, Crh, Srh, UrT, UiT, out, n);
}

// Round 14
// 966.733 us; speedup vs baseline: 1.7901x; 1.2835x over previous
//
#include <hip/hip_runtime.h>
#include <hip/hip_bf16.h>
#include <hip/hip_fp16.h>

#define MAXPH 0.78539816339744831f
typedef unsigned short ushort_t;

__device__ __forceinline__ float wsum64(float v) {
#pragma unroll
  for (int o = 32; o > 0; o >>= 1) v += __shfl_xor(v, o);
  return v;
}
__device__ __forceinline__ float bf2f(ushort_t u) {
  return __uint_as_float(((unsigned)u) << 16);
}

// ---- kInit: zero cnt/cur/AdjU; last block also preps Wg1/C0G1
__global__ void kInit(unsigned* __restrict__ cnt, unsigned* __restrict__ cur, int n,
                      unsigned* __restrict__ AdjU,
                      const float* __restrict__ ln_g, const float* __restrict__ ln_b,
                      const float* __restrict__ w1, const float* __restrict__ b1,
                      float* __restrict__ Wg1, float* __restrict__ C0G1) {
  int t = blockIdx.x * blockDim.x + threadIdx.x;
  int st = gridDim.x * blockDim.x;
  for (int i = t; i < n; i += st) {
    cnt[i] = 0u;
    cur[i] = 0u;
  }
  for (int i = t; i < 4096; i += st) AdjU[i] = 0u;
  if (blockIdx.x == gridDim.x - 1) {
    int tt = threadIdx.x;
    for (int idx = tt; idx < 4096; idx += 256) {
      int j = idx >> 5;
      Wg1[idx] = ln_g[j] * w1[idx];
    }
    if (tt < 32) {
      float c0 = b1[tt], g1 = 0.f;
      for (int j = 0; j < 128; ++j) {
        float w = w1[j * 32 + tt];
        c0 = fmaf(ln_b[j], w, c0);
        g1 = fmaf(ln_g[j], w, g1);
      }
      C0G1[tt] = c0;
      C0G1[32 + tt] = g1;
    }
  }
}

// ---- kCount: per-dst-node histogram + masked AdjU build (edge-parallel)
__global__ void kCount(const int* __restrict__ ei, int ne, unsigned* __restrict__ cnt,
                       unsigned* __restrict__ AdjU) {
  int t = blockIdx.x * blockDim.x + threadIdx.x;
  int st = gridDim.x * blockDim.x;
  for (int e = t; e < ne; e += st) {
    int s = ei[e];
    int d = ei[ne + e];
    atomicAdd(&cnt[d], 1u);
    if ((unsigned)(s | d) < 64u) atomicAdd(&AdjU[d * 64 + s], 1u);
  }
}

// ---- kScan: exclusive prefix over n counters (single block, 2-level)
__global__ __launch_bounds__(1024) void kScan(const unsigned* __restrict__ cnt,
                                              unsigned* __restrict__ off, int n) {
  __shared__ unsigned wsum[16];
  const int t = threadIdx.x;
  const int C = (n + 1023) >> 10;
  const int lo = t * C;
  const int hi = min(lo + C, n);
  unsigned s = 0;
  for (int i = lo; i < hi; ++i) s += cnt[i];
  unsigned v = s;
#pragma unroll
  for (int o = 1; o < 64; o <<= 1) {
    unsigned u = __shfl_up(v, o);
    if ((t & 63) >= o) v += u;
  }
  if ((t & 63) == 63) wsum[t >> 6] = v;
  __syncthreads();
  if (t == 0) {
    unsigned a = 0;
    for (int i = 0; i < 16; ++i) {
      unsigned c = wsum[i];
      wsum[i] = a;
      a += c;
    }
  }
  __syncthreads();
  unsigned run = wsum[t >> 6] + (v - s);
  for (int i = lo; i < hi; ++i) {
    off[i] = run;
    run += cnt[i];
  }
  if (t == 1023) off[n] = run;
}

// ---- kNode: LN -> h -> mag -> record {h bf16[64], As bf16[32], S12 f32[2]}; Ad; self-loop -> Crh/Srh
__global__ void kNode(const float* __restrict__ x, const float* __restrict__ Wr,
                      const float* __restrict__ Wg1, const float* __restrict__ C0G1,
                      const float* __restrict__ w2, const float* __restrict__ b2,
                      ushort_t* __restrict__ R, __hip_bfloat16* __restrict__ Ad,
                      __half* __restrict__ Crh, __half* __restrict__ Srh, int n) {
  __shared__ float sWr[4096];
  __shared__ float sWg1[4096];
  for (int i = threadIdx.x; i < 4096; i += blockDim.x) {
    sWr[i] = Wr[i];
    sWg1[i] = Wg1[i];
  }
  __syncthreads();
  const int lane = threadIdx.x & 63;
  const int k = lane & 31;
  const int half = lane >> 5;
  const float c0r = C0G1[k], g1r = C0G1[32 + k], w2r = w2[k], b2r = b2[0];
  const float* wg = sWg1 + half * 2048;
  const int wid = (blockIdx.x * blockDim.x + threadIdx.x) >> 6;
  const int nw = (gridDim.x * blockDim.x) >> 6;
  for (int node = wid; node < n; node += nw) {
    const float xv = x[node * 64 + lane];
    float s1 = wsum64(xv);
    float s2 = wsum64(xv * xv);
    float mean = s1 * 0.015625f;
    float var = fmaf(-mean, mean, s2 * 0.015625f);
    float rstd = rsqrtf(var + 1e-5f);
    float xr = (xv - mean) * rstd;
    float hv = 0.f;
#pragma unroll
    for (int m = 0; m < 64; ++m) hv = fmaf(__shfl(xr, m), sWr[m * 64 + lane], hv);
    float mag = sqrtf(fmaf(hv, hv, 1e-8f));
    float cm = fminf(mag, 10.f);
    float t1 = wsum64(cm);
    float t2 = wsum64(cm * cm);
    float acc = 0.f;
#pragma unroll
    for (int m = 0; m < 64; ++m) acc = fmaf(__shfl(cm, m), wg[m * 32 + k], acc);
    ushort_t* rn = R + (size_t)node * 128;
    __hip_bfloat16 hb = __float2bfloat16(hv);
    rn[lane] = *(ushort_t*)&hb;
    __hip_bfloat16 ab = __float2bfloat16(acc);
    if (half == 0) Ad[(size_t)node * 32 + k] = ab;
    else           rn[64 + k] = *(ushort_t*)&ab;
    if (lane == 0) {
      float* sp = (float*)(rn + 96);
      sp[0] = t1;
      sp[1] = t2;
    }
    // self-loop (i,i), ew=1 -> clip=1
    float meanE = t1 * 0.015625f;
    float varE = fmaf(-meanE, meanE, t2 * 0.015625f);
    float rstdE = rsqrtf(varE + 1e-5f);
    float hsum = acc + __shfl_xor(acc, 32);
    float pre = fmaf(rstdE, fmaf(-meanE, g1r, hsum), c0r);
    float contrib = fmaxf(pre, 0.f) * w2r;
    float z = fmaf(wsum64(contrib), 0.5f, b2r);
    float coup = 1.f / (1.f + expf(-z));
    float ph = fminf(0.3f * coup, MAXPH);
    float sn, cs;
    sincosf(ph, &sn, &cs);
    Crh[(size_t)node * 64 + lane] = __float2half(hv * cs);
    Srh[(size_t)node * 64 + lane] = __float2half(hv * sn);
  }
}

// ---- kPhaseFill: lane-per-edge phase compute, write {s,cos,sin} to dst-sorted slot
__global__ void kPhaseFill(const int* __restrict__ ei, const float* __restrict__ ew, int ne,
                           const ushort_t* __restrict__ R, const __hip_bfloat16* __restrict__ Ad,
                           const float* __restrict__ C0G1, const float* __restrict__ w2,
                           const float* __restrict__ b2,
                           const unsigned* __restrict__ off, unsigned* __restrict__ cur,
                           int* __restrict__ recS, float2* __restrict__ recCS) {
  const float b2r = b2[0];
  int t = blockIdx.x * blockDim.x + threadIdx.x;
  int st = gridDim.x * blockDim.x;
  for (int e = t; e < ne; e += st) {
    int s = ei[e];
    int d = ei[ne + e];
    const ushort_t* rs = R + (size_t)s * 128;
    const ushort_t* rd = R + (size_t)d * 128;
    float2 ps = *(const float2*)(rs + 96);
    float2 pd = *(const float2*)(rd + 96);
    float meanE = (ps.x + pd.x) * 0.0078125f;
    float varE = fmaf(-meanE, meanE, (ps.y + pd.y) * 0.0078125f);
    float rstdE = rsqrtf(varE + 1e-5f);
    const uint4* asq = (const uint4*)(rs + 64);
    const uint4* adq = (const uint4*)(Ad + (size_t)d * 32);
    float z = b2r;
#pragma unroll
    for (int q = 0; q < 4; ++q) {
      uint4 ua = adq[q];
      uint4 ub = asq[q];
      unsigned av[4] = {ua.x, ua.y, ua.z, ua.w};
      unsigned bv[4] = {ub.x, ub.y, ub.z, ub.w};
#pragma unroll
      for (int p = 0; p < 4; ++p) {
        int k0 = q * 8 + p * 2;
        float a0 = __uint_as_float(av[p] << 16);
        float a1 = __uint_as_float(av[p] & 0xFFFF0000u);
        float b0 = __uint_as_float(bv[p] << 16);
        float b1 = __uint_as_float(bv[p] & 0xFFFF0000u);
        float pre0 = fmaf(rstdE, fmaf(-meanE, C0G1[32 + k0], a0 + b0), C0G1[k0]);
        float pre1 = fmaf(rstdE, fmaf(-meanE, C0G1[32 + k0 + 1], a1 + b1), C0G1[k0 + 1]);
        z = fmaf(fmaxf(pre0, 0.f), w2[k0], z);
        z = fmaf(fmaxf(pre1, 0.f), w2[k0 + 1], z);
      }
    }
    float coup = 1.f / (1.f + expf(-z));
    float cw = fminf(fmaxf(ew[e], 0.1f), 2.f);
    float ph = fminf(0.3f * coup * cw, MAXPH);
    float sn, cs;
    sincosf(ph, &sn, &cs);
    unsigned p = atomicAdd(&cur[d], 1u);
    unsigned pos = off[d] + p;
    recS[pos] = s;
    recCS[pos] = make_float2(cs, sn);
  }
}

// ---- kScatter: wave-per-node register-accumulate gather; no shfl, no atomics
__global__ __launch_bounds__(256) void kScatter(
    const unsigned* __restrict__ off, const int* __restrict__ recS,
    const float2* __restrict__ recCS, const ushort_t* __restrict__ R,
    __half* __restrict__ Crh, __half* __restrict__ Srh, int n) {
  const int lane = threadIdx.x & 63;
  const int wid = (blockIdx.x * blockDim.x + threadIdx.x) >> 6;
  const int nw = (gridDim.x * blockDim.x) >> 6;
  for (int d = wid; d < n; d += nw) {
    unsigned u0 = off[d], u1 = off[d + 1];
    float accR = 0.f, accI = 0.f;
    unsigned j = u0;
    for (; j + 8 <= u1; j += 8) {
      int s8[8];
      float2 c8[8];
#pragma unroll
      for (int k = 0; k < 8; ++k) {
        s8[k] = recS[j + k];
        c8[k] = recCS[j + k];
      }
#pragma unroll
      for (int k = 0; k < 8; ++k) {
        float hv = bf2f(R[(size_t)s8[k] * 128 + lane]);
        accR = fmaf(hv, c8[k].x, accR);
        accI = fmaf(hv, c8[k].y, accI);
      }
    }
    for (; j < u1; ++j) {
      int s = recS[j];
      float2 c = recCS[j];
      float hv = bf2f(R[(size_t)s * 128 + lane]);
      accR = fmaf(hv, c.x, accR);
      accI = fmaf(hv, c.y, accI);
    }
    size_t idx = (size_t)d * 64 + lane;
    Crh[idx] = __float2half(__half2float(Crh[idx]) + accR);
    Srh[idx] = __float2half(__half2float(Srh[idx]) + accI);
  }
}

// ---- kGcnExpm: single block — AdjU (prebuilt) -> GCN x2 + pool + MLP + expm -> U^T
__global__ __launch_bounds__(1024) void kGcnExpm(
    const unsigned* __restrict__ AdjU,
    const float* __restrict__ g1w, const float* __restrict__ g1b,
    const float* __restrict__ g2w, const float* __restrict__ g2b,
    const float* __restrict__ aw1, const float* __restrict__ ab1,
    const float* __restrict__ aw2, const float* __restrict__ ab2,
    const float* __restrict__ aw3, const float* __restrict__ ab3,
    float* __restrict__ Bg, float* __restrict__ UrT, float* __restrict__ UiT) {
  __shared__ float SH[8192];
  __shared__ float sdv[64], sts[64], sgp[64], sz1[64], sz2[64];
  const int tid = threadIdx.x;
  for (int i = tid; i < 4096; i += 1024) SH[i] = (float)AdjU[i];
  __syncthreads();
  if (tid < 64) {
    float deg = 1.f;
    for (int s2 = 0; s2 < 64; ++s2) deg += SH[tid * 64 + s2];
    sdv[tid] = rsqrtf(deg);
  }
  __syncthreads();
  if (tid < 64) {
    float a = 0.f;
    for (int s2 = 0; s2 < 64; ++s2) a = fmaf(SH[tid * 64 + s2], sdv[s2], a);
    sts[tid] = a;
  }
  __syncthreads();
  float* h1 = SH + 4096;
  for (int idx = tid; idx < 4096; idx += 1024) {
    int d = idx >> 6, kk = idx & 63;
    h1[idx] = fmaxf(fmaf(g1w[kk], fmaf(sts[d], sdv[d], sdv[d] * sdv[d]), g1b[kk]), 0.f);
  }
  __syncthreads();
  const int i = tid >> 4, j0 = (tid & 15) << 2;
  float xw[4] = {0, 0, 0, 0};
  for (int m = 0; m < 64; ++m) {
    float hm = h1[i * 64 + m];
    const float* w = g2w + m * 64 + j0;
#pragma unroll
    for (int q = 0; q < 4; ++q) xw[q] = fmaf(hm, w[q], xw[q]);
  }
  __syncthreads();
#pragma unroll
  for (int q = 0; q < 4; ++q) h1[i * 64 + j0 + q] = xw[q];
  __syncthreads();
  {
    float a[4] = {0, 0, 0, 0};
    for (int s2 = 0; s2 < 64; ++s2) {
      float w = SH[i * 64 + s2] * sdv[s2];
      const float* xr = h1 + s2 * 64 + j0;
#pragma unroll
      for (int q = 0; q < 4; ++q) a[q] = fmaf(w, xr[q], a[q]);
    }
    float di = sdv[i], sc = di * di;
    float h2[4];
#pragma unroll
    for (int q = 0; q < 4; ++q)
      h2[q] = fmaf(a[q], di, fmaf(sc, h1[i * 64 + j0 + q], g2b[j0 + q]));
    __syncthreads();
#pragma unroll
    for (int q = 0; q < 4; ++q) h1[i * 64 + j0 + q] = h2[q];
  }
  __syncthreads();
  if (tid < 64) {
    float a = 0.f;
    for (int d = 0; d < 64; ++d) a += h1[d * 64 + tid];
    sgp[tid] = a * 0.015625f;
  }
  __syncthreads();
  if (tid < 64) {
    float a = ab1[tid];
    for (int m = 0; m < 64; ++m) a = fmaf(sgp[m], aw1[m * 64 + tid], a);
    sz1[tid] = fmaxf(a, 0.f);
  }
  __syncthreads();
  if (tid < 64) {
    float a = ab2[tid];
    for (int m = 0; m < 64; ++m) a = fmaf(sz1[m], aw2[m * 64 + tid], a);
    sz2[tid] = fmaxf(a, 0.f);
  }
  __syncthreads();
  for (int p4 = 0; p4 < 4; ++p4) {
    int rc = tid + p4 * 1024;
    float a = ab3[rc];
    for (int m = 0; m < 64; ++m) a = fmaf(sz2[m], aw3[m * 4096 + rc], a);
    SH[rc] = tanhf(a);
  }
  __syncthreads();
  const float SCC = 0.0015625f;  // 0.1*0.5/32
  for (int idx = tid; idx < 4096; idx += 1024) {
    int r = idx >> 6, c = idx & 63;
    float pr = SH[r * 64 + c], pt = SH[c * 64 + r];
    Bg[idx] = (pr - pt) * SCC;
    Bg[4096 + idx] = (pr + pt) * SCC;
  }
  __syncthreads();
  float* Xr = SH;
  float* Xi = SH + 4096;
  for (int idx = tid; idx < 4096; idx += 1024) {
    int r = idx >> 6, c = idx & 63;
    Xr[idx] = (r == c ? 1.f : 0.f) + Bg[idx] * (1.f / 6.f);
    Xi[idx] = Bg[4096 + idx] * (1.f / 6.f);
  }
  __syncthreads();
  for (int kk = 5; kk >= 1; --kk) {
    float ar[4] = {0, 0, 0, 0}, ai[4] = {0, 0, 0, 0};
    const float* brr = Bg + i * 64;
    const float* bir = Bg + 4096 + i * 64;
    for (int m = 0; m < 64; ++m) {
      float br = brr[m], bi = bir[m];
#pragma unroll
      for (int q = 0; q < 4; ++q) {
        float xr = Xr[m * 64 + j0 + q], xi = Xi[m * 64 + j0 + q];
        ar[q] = fmaf(br, xr, fmaf(-bi, xi, ar[q]));
        ai[q] = fmaf(br, xi, fmaf(bi, xr, ai[q]));
      }
    }
    __syncthreads();
    float inv = 1.f / (float)kk;
#pragma unroll
    for (int q = 0; q < 4; ++q) {
      int c = j0 + q;
      Xr[i * 64 + c] = (i == c ? 1.f : 0.f) + ar[q] * inv;
      Xi[i * 64 + c] = ai[q] * inv;
    }
    __syncthreads();
  }
  for (int sq = 0; sq < 5; ++sq) {
    float ar[4] = {0, 0, 0, 0}, ai[4] = {0, 0, 0, 0};
    for (int m = 0; m < 64; ++m) {
      float br = Xr[i * 64 + m], bi = Xi[i * 64 + m];
#pragma unroll
      for (int q = 0; q < 4; ++q) {
        float xr = Xr[m * 64 + j0 + q], xi = Xi[m * 64 + j0 + q];
        ar[q] = fmaf(br, xr, fmaf(-bi, xi, ar[q]));
        ai[q] = fmaf(br, xi, fmaf(bi, xr, ai[q]));
      }
    }
    __syncthreads();
#pragma unroll
    for (int q = 0; q < 4; ++q) {
      Xr[i * 64 + j0 + q] = ar[q];
      Xi[i * 64 + j0 + q] = ai[q];
    }
    __syncthreads();
  }
  for (int idx = tid; idx < 4096; idx += 1024) {
    int a2 = idx >> 6, b2i = idx & 63;
    UrT[idx] = Xr[b2i * 64 + a2];
    UiT[idx] = Xi[b2i * 64 + a2];
  }
}

// ---- kFinal: aggr = [Cr,Sr] x U^T (complex), out = 0.5*aggr + 0.5*LN(x)
__global__ void kFinal(const float* __restrict__ x, const __half* __restrict__ Crh,
                       const __half* __restrict__ Srh, const float* __restrict__ UrT,
                       const float* __restrict__ UiT, float* __restrict__ out, int n) {
  __shared__ float sUr[4096], sUi[4096];
  for (int i = threadIdx.x; i < 4096; i += blockDim.x) {
    sUr[i] = UrT[i];
    sUi[i] = UiT[i];
  }
  __syncthreads();
  const int lane = threadIdx.x & 63;
  const int wid = (blockIdx.x * blockDim.x + threadIdx.x) >> 6;
  const int nw = (gridDim.x * blockDim.x) >> 6;
  const size_t imag_off = (size_t)n * 64;
  for (int node = wid; node < n; node += nw) {
    float cr = __half2float(Crh[(size_t)node * 64 + lane]);
    float sr = __half2float(Srh[(size_t)node * 64 + lane]);
    float ar = 0.f, ai = 0.f;
#pragma unroll
    for (int m = 0; m < 64; ++m) {
      float crm = __shfl(cr, m), srm = __shfl(sr, m);
      float ur = sUr[m * 64 + lane], ui = sUi[m * 64 + lane];
      ar = fmaf(crm, ur, fmaf(-srm, ui, ar));
      ai = fmaf(crm, ui, fmaf(srm, ur, ai));
    }
    float xv = x[node * 64 + lane];
    float s1 = wsum64(xv);
    float s2 = wsum64(xv * xv);
    float mean = s1 * 0.015625f;
    float var = fmaf(-mean, mean, s2 * 0.015625f);
    float xr = (xv - mean) * rsqrtf(var + 1e-5f);
    out[node * 64 + lane] = 0.5f * (ar + xr);
    out[imag_off + node * 64 + lane] = 0.5f * ai;
  }
}

extern "C" void kernel_launch(void* const* d_in, const int* in_sizes, int n_in,
                              void* d_out, int out_size, void* d_ws, size_t ws_size,
                              hipStream_t stream) {
  const float* x    = (const float*)d_in[0];
  const int*   ei   = (const int*)d_in[1];
  const float* ew   = (const float*)d_in[2];
  const float* Wr   = (const float*)d_in[3];
  const float* ln_g = (const float*)d_in[5];
  const float* ln_b = (const float*)d_in[6];
  const float* w1   = (const float*)d_in[7];
  const float* b1   = (const float*)d_in[8];
  const float* w2   = (const float*)d_in[9];
  const float* b2   = (const float*)d_in[10];
  const float* g1w  = (const float*)d_in[11];
  const float* g1b  = (const float*)d_in[12];
  const float* g2w  = (const float*)d_in[13];
  const float* g2b  = (const float*)d_in[14];
  const float* aw1  = (const float*)d_in[15];
  const float* ab1  = (const float*)d_in[16];
  const float* aw2  = (const float*)d_in[17];
  const float* ab2  = (const float*)d_in[18];
  const float* aw3  = (const float*)d_in[19];
  const float* ab3  = (const float*)d_in[20];
  const int n = in_sizes[0] / 64;
  const int e = in_sizes[1] / 2;
  float* out = (float*)d_out;

  float* ws = (float*)d_ws;
  float* Wg1  = ws;                           // 4096
  float* C0G1 = ws + 4096;                    // 64
  float* UrT  = ws + 4160;                    // 4096
  float* UiT  = ws + 8256;                    // 4096
  float* Bg   = ws + 12352;                   // 8192
  unsigned* AdjU = (unsigned*)(ws + 20544);   // 4096 u32
  unsigned* cnt = AdjU + 4096;                // n
  unsigned* off = cnt + n;                    // n+1
  unsigned* cur = off + n + 1;                // n
  size_t p0 = (20544 + 4096 + 3 * (size_t)n + 1 + 63) & ~(size_t)63;
  int* recS = (int*)(ws + p0);                // e
  size_t p1 = (p0 + (size_t)e + 1) & ~(size_t)1;
  float2* recCS = (float2*)(ws + p1);         // 2e
  size_t p2 = p1 + 2 * (size_t)e;
  ushort_t* R = (ushort_t*)(ws + p2);         // 64n f32-units
  size_t p3 = p2 + 64 * (size_t)n;
  __hip_bfloat16* Ad = (__hip_bfloat16*)(ws + p3);  // 16n
  size_t p4 = p3 + 16 * (size_t)n;
  __half* Crh = (__half*)(ws + p4);           // 32n
  __half* Srh = (__half*)(ws + p4 + 32 * (size_t)n);  // 32n

  kInit<<<512, 256, 0, stream>>>(cnt, cur, n, AdjU, ln_g, ln_b, w1, b1, Wg1, C0G1);
  kNode<<<1024, 256, 0, stream>>>(x, Wr, Wg1, C0G1, w2, b2, R, Ad, Crh, Srh, n);
  kCount<<<1024, 256, 0, stream>>>(ei, e, cnt, AdjU);
  kScan<<<1, 1024, 0, stream>>>(cnt, off, n);
  kPhaseFill<<<1024, 256, 0, stream>>>(ei, ew, e, R, Ad, C0G1, w2, b2, off, cur, recS, recCS);
  kScatter<<<2048, 256, 0, stream>>>(off, recS, recCS, R, Crh, Srh, n);
  kGcnExpm<<<1, 1024, 0, stream>>>(AdjU, g1w, g1b, g2w, g2b, aw1, ab1, aw2, ab2, aw3, ab3,
                                   Bg, UrT, UiT);
  kFinal<<<1024, 256, 0, stream>>>(x, Crh, Srh, UrT, UiT, out, n);
}

// Round 15
// 675.135 us; speedup vs baseline: 2.5633x; 1.4319x over previous
//
#include <hip/hip_runtime.h>
#include <hip/hip_bf16.h>
#include <hip/hip_fp16.h>

#define MAXPH 0.78539816339744831f
typedef unsigned short ushort_t;
typedef _Float16 half8 __attribute__((ext_vector_type(8)));
typedef float f32x4 __attribute__((ext_vector_type(4)));

__device__ __forceinline__ float wsum64(float v) {
#pragma unroll
  for (int o = 32; o > 0; o >>= 1) v += __shfl_xor(v, o);
  return v;
}
__device__ __forceinline__ float bf2f(ushort_t u) {
  return __uint_as_float(((unsigned)u) << 16);
}

// ---- kInit: zero cnt/cur/AdjU; last block also preps Wg1/C0G1
__global__ void kInit(unsigned* __restrict__ cnt, unsigned* __restrict__ cur, int n,
                      unsigned* __restrict__ AdjU,
                      const float* __restrict__ ln_g, const float* __restrict__ ln_b,
                      const float* __restrict__ w1, const float* __restrict__ b1,
                      float* __restrict__ Wg1, float* __restrict__ C0G1) {
  int t = blockIdx.x * blockDim.x + threadIdx.x;
  int st = gridDim.x * blockDim.x;
  for (int i = t; i < n; i += st) {
    cnt[i] = 0u;
    cur[i] = 0u;
  }
  for (int i = t; i < 4096; i += st) AdjU[i] = 0u;
  if (blockIdx.x == gridDim.x - 1) {
    int tt = threadIdx.x;
    for (int idx = tt; idx < 4096; idx += 256) {
      int j = idx >> 5;
      Wg1[idx] = ln_g[j] * w1[idx];
    }
    if (tt < 32) {
      float c0 = b1[tt], g1 = 0.f;
      for (int j = 0; j < 128; ++j) {
        float w = w1[j * 32 + tt];
        c0 = fmaf(ln_b[j], w, c0);
        g1 = fmaf(ln_g[j], w, g1);
      }
      C0G1[tt] = c0;
      C0G1[32 + tt] = g1;
    }
  }
}

// ---- kCount: per-dst-node histogram + masked AdjU build
__global__ void kCount(const int* __restrict__ ei, int ne, unsigned* __restrict__ cnt,
                       unsigned* __restrict__ AdjU) {
  int t = blockIdx.x * blockDim.x + threadIdx.x;
  int st = gridDim.x * blockDim.x;
  for (int e = t; e < ne; e += st) {
    int s = ei[e];
    int d = ei[ne + e];
    atomicAdd(&cnt[d], 1u);
    if ((unsigned)(s | d) < 64u) atomicAdd(&AdjU[d * 64 + s], 1u);
  }
}

// ---- kScan: exclusive prefix over n counters
__global__ __launch_bounds__(1024) void kScan(const unsigned* __restrict__ cnt,
                                              unsigned* __restrict__ off, int n) {
  __shared__ unsigned wsum[16];
  const int t = threadIdx.x;
  const int C = (n + 1023) >> 10;
  const int lo = t * C;
  const int hi = min(lo + C, n);
  unsigned s = 0;
  for (int i = lo; i < hi; ++i) s += cnt[i];
  unsigned v = s;
#pragma unroll
  for (int o = 1; o < 64; o <<= 1) {
    unsigned u = __shfl_up(v, o);
    if ((t & 63) >= o) v += u;
  }
  if ((t & 63) == 63) wsum[t >> 6] = v;
  __syncthreads();
  if (t == 0) {
    unsigned a = 0;
    for (int i = 0; i < 16; ++i) {
      unsigned c = wsum[i];
      wsum[i] = a;
      a += c;
    }
  }
  __syncthreads();
  unsigned run = wsum[t >> 6] + (v - s);
  for (int i = lo; i < hi; ++i) {
    off[i] = run;
    run += cnt[i];
  }
  if (t == 1023) off[n] = run;
}

// ---- kNode: LN -> h -> mag -> record {h bf16[64], As bf16[32], S12 f32[2]}; Ad; self-loop -> Crh/Srh
__global__ void kNode(const float* __restrict__ x, const float* __restrict__ Wr,
                      const float* __restrict__ Wg1, const float* __restrict__ C0G1,
                      const float* __restrict__ w2, const float* __restrict__ b2,
                      ushort_t* __restrict__ R, __hip_bfloat16* __restrict__ Ad,
                      __half* __restrict__ Crh, __half* __restrict__ Srh, int n) {
  __shared__ float sWr[4096];
  __shared__ float sWg1[4096];
  for (int i = threadIdx.x; i < 4096; i += blockDim.x) {
    sWr[i] = Wr[i];
    sWg1[i] = Wg1[i];
  }
  __syncthreads();
  const int lane = threadIdx.x & 63;
  const int k = lane & 31;
  const int half = lane >> 5;
  const float c0r = C0G1[k], g1r = C0G1[32 + k], w2r = w2[k], b2r = b2[0];
  const float* wg = sWg1 + half * 2048;
  const int wid = (blockIdx.x * blockDim.x + threadIdx.x) >> 6;
  const int nw = (gridDim.x * blockDim.x) >> 6;
  for (int node = wid; node < n; node += nw) {
    const float xv = x[node * 64 + lane];
    float s1 = wsum64(xv);
    float s2 = wsum64(xv * xv);
    float mean = s1 * 0.015625f;
    float var = fmaf(-mean, mean, s2 * 0.015625f);
    float rstd = rsqrtf(var + 1e-5f);
    float xr = (xv - mean) * rstd;
    float hv = 0.f;
#pragma unroll
    for (int m = 0; m < 64; ++m) hv = fmaf(__shfl(xr, m), sWr[m * 64 + lane], hv);
    float mag = sqrtf(fmaf(hv, hv, 1e-8f));
    float cm = fminf(mag, 10.f);
    float t1 = wsum64(cm);
    float t2 = wsum64(cm * cm);
    float acc = 0.f;
#pragma unroll
    for (int m = 0; m < 64; ++m) acc = fmaf(__shfl(cm, m), wg[m * 32 + k], acc);
    ushort_t* rn = R + (size_t)node * 128;
    __hip_bfloat16 hb = __float2bfloat16(hv);
    rn[lane] = *(ushort_t*)&hb;
    __hip_bfloat16 ab = __float2bfloat16(acc);
    if (half == 0) Ad[(size_t)node * 32 + k] = ab;
    else           rn[64 + k] = *(ushort_t*)&ab;
    if (lane == 0) {
      float* sp = (float*)(rn + 96);
      sp[0] = t1;
      sp[1] = t2;
    }
    // self-loop (i,i), ew=1 -> clip=1
    float meanE = t1 * 0.015625f;
    float varE = fmaf(-meanE, meanE, t2 * 0.015625f);
    float rstdE = rsqrtf(varE + 1e-5f);
    float hsum = acc + __shfl_xor(acc, 32);
    float pre = fmaf(rstdE, fmaf(-meanE, g1r, hsum), c0r);
    float contrib = fmaxf(pre, 0.f) * w2r;
    float z = fmaf(wsum64(contrib), 0.5f, b2r);
    float coup = 1.f / (1.f + expf(-z));
    float ph = fminf(0.3f * coup, MAXPH);
    float sn, cs;
    sincosf(ph, &sn, &cs);
    Crh[(size_t)node * 64 + lane] = __float2half(hv * cs);
    Srh[(size_t)node * 64 + lane] = __float2half(hv * sn);
  }
}

// ---- kPhaseFill: lane-per-edge phase compute, write {s,cos,sin} to dst-sorted slot
__global__ void kPhaseFill(const int* __restrict__ ei, const float* __restrict__ ew, int ne,
                           const ushort_t* __restrict__ R, const __hip_bfloat16* __restrict__ Ad,
                           const float* __restrict__ C0G1, const float* __restrict__ w2,
                           const float* __restrict__ b2,
                           const unsigned* __restrict__ off, unsigned* __restrict__ cur,
                           int* __restrict__ recS, float2* __restrict__ recCS) {
  const float b2r = b2[0];
  int t = blockIdx.x * blockDim.x + threadIdx.x;
  int st = gridDim.x * blockDim.x;
  for (int e = t; e < ne; e += st) {
    int s = ei[e];
    int d = ei[ne + e];
    const ushort_t* rs = R + (size_t)s * 128;
    const ushort_t* rd = R + (size_t)d * 128;
    float2 ps = *(const float2*)(rs + 96);
    float2 pd = *(const float2*)(rd + 96);
    float meanE = (ps.x + pd.x) * 0.0078125f;
    float varE = fmaf(-meanE, meanE, (ps.y + pd.y) * 0.0078125f);
    float rstdE = rsqrtf(varE + 1e-5f);
    const uint4* asq = (const uint4*)(rs + 64);
    const uint4* adq = (const uint4*)(Ad + (size_t)d * 32);
    float z = b2r;
#pragma unroll
    for (int q = 0; q < 4; ++q) {
      uint4 ua = adq[q];
      uint4 ub = asq[q];
      unsigned av[4] = {ua.x, ua.y, ua.z, ua.w};
      unsigned bv[4] = {ub.x, ub.y, ub.z, ub.w};
#pragma unroll
      for (int p = 0; p < 4; ++p) {
        int k0 = q * 8 + p * 2;
        float a0 = __uint_as_float(av[p] << 16);
        float a1 = __uint_as_float(av[p] & 0xFFFF0000u);
        float b0 = __uint_as_float(bv[p] << 16);
        float b1 = __uint_as_float(bv[p] & 0xFFFF0000u);
        float pre0 = fmaf(rstdE, fmaf(-meanE, C0G1[32 + k0], a0 + b0), C0G1[k0]);
        float pre1 = fmaf(rstdE, fmaf(-meanE, C0G1[32 + k0 + 1], a1 + b1), C0G1[k0 + 1]);
        z = fmaf(fmaxf(pre0, 0.f), w2[k0], z);
        z = fmaf(fmaxf(pre1, 0.f), w2[k0 + 1], z);
      }
    }
    float coup = 1.f / (1.f + expf(-z));
    float cw = fminf(fmaxf(ew[e], 0.1f), 2.f);
    float ph = fminf(0.3f * coup * cw, MAXPH);
    float sn, cs;
    sincosf(ph, &sn, &cs);
    unsigned p = atomicAdd(&cur[d], 1u);
    unsigned pos = off[d] + p;
    recS[pos] = s;
    recCS[pos] = make_float2(cs, sn);
  }
}

// ---- kScatter: wave-per-node register-accumulate gather
__global__ __launch_bounds__(256) void kScatter(
    const unsigned* __restrict__ off, const int* __restrict__ recS,
    const float2* __restrict__ recCS, const ushort_t* __restrict__ R,
    __half* __restrict__ Crh, __half* __restrict__ Srh, int n) {
  const int lane = threadIdx.x & 63;
  const int wid = (blockIdx.x * blockDim.x + threadIdx.x) >> 6;
  const int nw = (gridDim.x * blockDim.x) >> 6;
  for (int d = wid; d < n; d += nw) {
    unsigned u0 = off[d], u1 = off[d + 1];
    float accR = 0.f, accI = 0.f;
    unsigned j = u0;
    for (; j + 8 <= u1; j += 8) {
      int s8[8];
      float2 c8[8];
#pragma unroll
      for (int k = 0; k < 8; ++k) {
        s8[k] = recS[j + k];
        c8[k] = recCS[j + k];
      }
#pragma unroll
      for (int k = 0; k < 8; ++k) {
        float hv = bf2f(R[(size_t)s8[k] * 128 + lane]);
        accR = fmaf(hv, c8[k].x, accR);
        accI = fmaf(hv, c8[k].y, accI);
      }
    }
    for (; j < u1; ++j) {
      int s = recS[j];
      float2 c = recCS[j];
      float hv = bf2f(R[(size_t)s * 128 + lane]);
      accR = fmaf(hv, c.x, accR);
      accI = fmaf(hv, c.y, accI);
    }
    size_t idx = (size_t)d * 64 + lane;
    Crh[idx] = __float2half(__half2float(Crh[idx]) + accR);
    Srh[idx] = __float2half(__half2float(Srh[idx]) + accI);
  }
}

// ---- kGcnExpm: single block — AdjU (prebuilt) -> GCN x2 + pool + MLP + expm -> U^T
__global__ __launch_bounds__(1024) void kGcnExpm(
    const unsigned* __restrict__ AdjU,
    const float* __restrict__ g1w, const float* __restrict__ g1b,
    const float* __restrict__ g2w, const float* __restrict__ g2b,
    const float* __restrict__ aw1, const float* __restrict__ ab1,
    const float* __restrict__ aw2, const float* __restrict__ ab2,
    const float* __restrict__ aw3, const float* __restrict__ ab3,
    float* __restrict__ Bg, float* __restrict__ UrT, float* __restrict__ UiT) {
  __shared__ float SH[8192];
  __shared__ float sdv[64], sts[64], sgp[64], sz1[64], sz2[64];
  const int tid = threadIdx.x;
  for (int i = tid; i < 4096; i += 1024) SH[i] = (float)AdjU[i];
  __syncthreads();
  if (tid < 64) {
    float deg = 1.f;
    for (int s2 = 0; s2 < 64; ++s2) deg += SH[tid * 64 + s2];
    sdv[tid] = rsqrtf(deg);
  }
  __syncthreads();
  if (tid < 64) {
    float a = 0.f;
    for (int s2 = 0; s2 < 64; ++s2) a = fmaf(SH[tid * 64 + s2], sdv[s2], a);
    sts[tid] = a;
  }
  __syncthreads();
  float* h1 = SH + 4096;
  for (int idx = tid; idx < 4096; idx += 1024) {
    int d = idx >> 6, kk = idx & 63;
    h1[idx] = fmaxf(fmaf(g1w[kk], fmaf(sts[d], sdv[d], sdv[d] * sdv[d]), g1b[kk]), 0.f);
  }
  __syncthreads();
  const int i = tid >> 4, j0 = (tid & 15) << 2;
  float xw[4] = {0, 0, 0, 0};
  for (int m = 0; m < 64; ++m) {
    float hm = h1[i * 64 + m];
    const float* w = g2w + m * 64 + j0;
#pragma unroll
    for (int q = 0; q < 4; ++q) xw[q] = fmaf(hm, w[q], xw[q]);
  }
  __syncthreads();
#pragma unroll
  for (int q = 0; q < 4; ++q) h1[i * 64 + j0 + q] = xw[q];
  __syncthreads();
  {
    float a[4] = {0, 0, 0, 0};
    for (int s2 = 0; s2 < 64; ++s2) {
      float w = SH[i * 64 + s2] * sdv[s2];
      const float* xr = h1 + s2 * 64 + j0;
#pragma unroll
      for (int q = 0; q < 4; ++q) a[q] = fmaf(w, xr[q], a[q]);
    }
    float di = sdv[i], sc = di * di;
    float h2[4];
#pragma unroll
    for (int q = 0; q < 4; ++q)
      h2[q] = fmaf(a[q], di, fmaf(sc, h1[i * 64 + j0 + q], g2b[j0 + q]));
    __syncthreads();
#pragma unroll
    for (int q = 0; q < 4; ++q) h1[i * 64 + j0 + q] = h2[q];
  }
  __syncthreads();
  if (tid < 64) {
    float a = 0.f;
    for (int d = 0; d < 64; ++d) a += h1[d * 64 + tid];
    sgp[tid] = a * 0.015625f;
  }
  __syncthreads();
  if (tid < 64) {
    float a = ab1[tid];
    for (int m = 0; m < 64; ++m) a = fmaf(sgp[m], aw1[m * 64 + tid], a);
    sz1[tid] = fmaxf(a, 0.f);
  }
  __syncthreads();
  if (tid < 64) {
    float a = ab2[tid];
    for (int m = 0; m < 64; ++m) a = fmaf(sz1[m], aw2[m * 64 + tid], a);
    sz2[tid] = fmaxf(a, 0.f);
  }
  __syncthreads();
  for (int p4 = 0; p4 < 4; ++p4) {
    int rc = tid + p4 * 1024;
    float a = ab3[rc];
    for (int m = 0; m < 64; ++m) a = fmaf(sz2[m], aw3[m * 4096 + rc], a);
    SH[rc] = tanhf(a);
  }
  __syncthreads();
  const float SCC = 0.0015625f;  // 0.1*0.5/32
  for (int idx = tid; idx < 4096; idx += 1024) {
    int r = idx >> 6, c = idx & 63;
    float pr = SH[r * 64 + c], pt = SH[c * 64 + r];
    Bg[idx] = (pr - pt) * SCC;
    Bg[4096 + idx] = (pr + pt) * SCC;
  }
  __syncthreads();
  float* Xr = SH;
  float* Xi = SH + 4096;
  for (int idx = tid; idx < 4096; idx += 1024) {
    int r = idx >> 6, c = idx & 63;
    Xr[idx] = (r == c ? 1.f : 0.f) + Bg[idx] * (1.f / 6.f);
    Xi[idx] = Bg[4096 + idx] * (1.f / 6.f);
  }
  __syncthreads();
  for (int kk = 5; kk >= 1; --kk) {
    float ar[4] = {0, 0, 0, 0}, ai[4] = {0, 0, 0, 0};
    const float* brr = Bg + i * 64;
    const float* bir = Bg + 4096 + i * 64;
    for (int m = 0; m < 64; ++m) {
      float br = brr[m], bi = bir[m];
#pragma unroll
      for (int q = 0; q < 4; ++q) {
        float xr = Xr[m * 64 + j0 + q], xi = Xi[m * 64 + j0 + q];
        ar[q] = fmaf(br, xr, fmaf(-bi, xi, ar[q]));
        ai[q] = fmaf(br, xi, fmaf(bi, xr, ai[q]));
      }
    }
    __syncthreads();
    float inv = 1.f / (float)kk;
#pragma unroll
    for (int q = 0; q < 4; ++q) {
      int c = j0 + q;
      Xr[i * 64 + c] = (i == c ? 1.f : 0.f) + ar[q] * inv;
      Xi[i * 64 + c] = ai[q] * inv;
    }
    __syncthreads();
  }
  for (int sq = 0; sq < 5; ++sq) {
    float ar[4] = {0, 0, 0, 0}, ai[4] = {0, 0, 0, 0};
    for (int m = 0; m < 64; ++m) {
      float br = Xr[i * 64 + m], bi = Xi[i * 64 + m];
#pragma unroll
      for (int q = 0; q < 4; ++q) {
        float xr = Xr[m * 64 + j0 + q], xi = Xi[m * 64 + j0 + q];
        ar[q] = fmaf(br, xr, fmaf(-bi, xi, ar[q]));
        ai[q] = fmaf(br, xi, fmaf(bi, xr, ai[q]));
      }
    }
    __syncthreads();
#pragma unroll
    for (int q = 0; q < 4; ++q) {
      Xr[i * 64 + j0 + q] = ar[q];
      Xi[i * 64 + j0 + q] = ai[q];
    }
    __syncthreads();
  }
  for (int idx = tid; idx < 4096; idx += 1024) {
    int a2 = idx >> 6, b2i = idx & 63;
    UrT[idx] = Xr[b2i * 64 + a2];
    UiT[idx] = Xi[b2i * 64 + a2];
  }
}

// ---- kFinalM: MFMA GEMM — OutR=[Cr|Sr]@[UrT;-UiT], OutI=[Cr|Sr]@[UiT;UrT]; +0.5*LN(x)
__global__ __launch_bounds__(256) void kFinalM(
    const float* __restrict__ x, const __half* __restrict__ Crh,
    const __half* __restrict__ Srh, const float* __restrict__ UrT,
    const float* __restrict__ UiT, float* __restrict__ out, int n, int ntiles) {
  __shared__ _Float16 bR[1024][8];  // fragment layout: slot = g*256 + c*64 + lane
  __shared__ _Float16 bI[1024][8];
  __shared__ float xrT[4][16][65];
  const int tid = threadIdx.x;
  const int lane = tid & 63;
  const int wave = tid >> 6;
  // build B fragments (B[k][col]: lane holds k=(l>>4)*8+j, col=l&15)
  for (int slot = tid; slot < 1024; slot += 256) {
    int g = slot >> 8;
    int c = (slot >> 6) & 3;
    int l = slot & 63;
    int col = g * 16 + (l & 15);
    int kb = c * 32 + ((l >> 4) << 3);
#pragma unroll
    for (int j = 0; j < 8; ++j) {
      int k = kb + j;
      float vr, vi;
      if (k < 64) {
        vr = UrT[k * 64 + col];
        vi = UiT[k * 64 + col];
      } else {
        vr = -UiT[(k - 64) * 64 + col];
        vi = UrT[(k - 64) * 64 + col];
      }
      bR[slot][j] = (_Float16)vr;
      bI[slot][j] = (_Float16)vi;
    }
  }
  __syncthreads();
  const int tile = blockIdx.x * 4 + wave;
  if (tile >= ntiles) return;
  const int base = tile << 4;
  // LN tile (16 nodes)
  for (int nn = 0; nn < 16; ++nn) {
    int node = min(base + nn, n - 1);
    float xv = x[(size_t)node * 64 + lane];
    float s1 = wsum64(xv);
    float s2 = wsum64(xv * xv);
    float mean = s1 * 0.015625f;
    float var = fmaf(-mean, mean, s2 * 0.015625f);
    xrT[wave][nn][lane] = (xv - mean) * rsqrtf(var + 1e-5f);
  }
  // A fragments: row=l&15 (node), k=(l>>4)*8+j
  const int row = lane & 15;
  const int node = min(base + row, n - 1);
  const int kb = (lane >> 4) << 3;
  const _Float16* crp = (const _Float16*)(Crh + (size_t)node * 64);
  const _Float16* srp = (const _Float16*)(Srh + (size_t)node * 64);
  half8 a0 = *(const half8*)(crp + kb);
  half8 a1 = *(const half8*)(crp + 32 + kb);
  half8 a2 = *(const half8*)(srp + kb);
  half8 a3 = *(const half8*)(srp + 32 + kb);
  const size_t imag_off = (size_t)n * 64;
  const int rgrp = (lane >> 4) << 2;
#pragma unroll
  for (int g = 0; g < 4; ++g) {
    f32x4 accR = {0.f, 0.f, 0.f, 0.f};
    f32x4 accI = {0.f, 0.f, 0.f, 0.f};
    const int sb = g * 256 + lane;
    half8 br0 = *(const half8*)&bR[sb][0];
    half8 br1 = *(const half8*)&bR[sb + 64][0];
    half8 br2 = *(const half8*)&bR[sb + 128][0];
    half8 br3 = *(const half8*)&bR[sb + 192][0];
    accR = __builtin_amdgcn_mfma_f32_16x16x32_f16(a0, br0, accR, 0, 0, 0);
    accR = __builtin_amdgcn_mfma_f32_16x16x32_f16(a1, br1, accR, 0, 0, 0);
    accR = __builtin_amdgcn_mfma_f32_16x16x32_f16(a2, br2, accR, 0, 0, 0);
    accR = __builtin_amdgcn_mfma_f32_16x16x32_f16(a3, br3, accR, 0, 0, 0);
    half8 bi0 = *(const half8*)&bI[sb][0];
    half8 bi1 = *(const half8*)&bI[sb + 64][0];
    half8 bi2 = *(const half8*)&bI[sb + 128][0];
    half8 bi3 = *(const half8*)&bI[sb + 192][0];
    accI = __builtin_amdgcn_mfma_f32_16x16x32_f16(a0, bi0, accI, 0, 0, 0);
    accI = __builtin_amdgcn_mfma_f32_16x16x32_f16(a1, bi1, accI, 0, 0, 0);
    accI = __builtin_amdgcn_mfma_f32_16x16x32_f16(a2, bi2, accI, 0, 0, 0);
    accI = __builtin_amdgcn_mfma_f32_16x16x32_f16(a3, bi3, accI, 0, 0, 0);
    const int col = g * 16 + (lane & 15);
#pragma unroll
    for (int reg = 0; reg < 4; ++reg) {
      int r = base + rgrp + reg;
      if (r < n) {
        out[(size_t)r * 64 + col] = 0.5f * (accR[reg] + xrT[wave][rgrp + reg][col]);
        out[imag_off + (size_t)r * 64 + col] = 0.5f * accI[reg];
      }
    }
  }
}

extern "C" void kernel_launch(void* const* d_in, const int* in_sizes, int n_in,
                              void* d_out, int out_size, void* d_ws, size_t ws_size,
                              hipStream_t stream) {
  const float* x    = (const float*)d_in[0];
  const int*   ei   = (const int*)d_in[1];
  const float* ew   = (const float*)d_in[2];
  const float* Wr   = (const float*)d_in[3];
  const float* ln_g = (const float*)d_in[5];
  const float* ln_b = (const float*)d_in[6];
  const float* w1   = (const float*)d_in[7];
  const float* b1   = (const float*)d_in[8];
  const float* w2   = (const float*)d_in[9];
  const float* b2   = (const float*)d_in[10];
  const float* g1w  = (const float*)d_in[11];
  const float* g1b  = (const float*)d_in[12];
  const float* g2w  = (const float*)d_in[13];
  const float* g2b  = (const float*)d_in[14];
  const float* aw1  = (const float*)d_in[15];
  const float* ab1  = (const float*)d_in[16];
  const float* aw2  = (const float*)d_in[17];
  const float* ab2  = (const float*)d_in[18];
  const float* aw3  = (const float*)d_in[19];
  const float* ab3  = (const float*)d_in[20];
  const int n = in_sizes[0] / 64;
  const int e = in_sizes[1] / 2;
  float* out = (float*)d_out;

  float* ws = (float*)d_ws;
  float* Wg1  = ws;                           // 4096
  float* C0G1 = ws + 4096;                    // 64
  float* UrT  = ws + 4160;                    // 4096
  float* UiT  = ws + 8256;                    // 4096
  float* Bg   = ws + 12352;                   // 8192
  unsigned* AdjU = (unsigned*)(ws + 20544);   // 4096 u32
  unsigned* cnt = AdjU + 4096;                // n
  unsigned* off = cnt + n;                    // n+1
  unsigned* cur = off + n + 1;                // n
  size_t p0 = (20544 + 4096 + 3 * (size_t)n + 1 + 63) & ~(size_t)63;
  int* recS = (int*)(ws + p0);                // e
  size_t p1 = (p0 + (size_t)e + 63) & ~(size_t)63;
  float2* recCS = (float2*)(ws + p1);         // 2e
  size_t p2 = (p1 + 2 * (size_t)e + 63) & ~(size_t)63;
  ushort_t* R = (ushort_t*)(ws + p2);         // 64n f32-units
  size_t p3 = (p2 + 64 * (size_t)n + 63) & ~(size_t)63;
  __hip_bfloat16* Ad = (__hip_bfloat16*)(ws + p3);  // 16n
  size_t p4 = (p3 + 16 * (size_t)n + 63) & ~(size_t)63;
  __half* Crh = (__half*)(ws + p4);           // 32n
  size_t p5 = (p4 + 32 * (size_t)n + 63) & ~(size_t)63;
  __half* Srh = (__half*)(ws + p5);           // 32n

  const int ntiles = (n + 15) >> 4;
  const int fblocks = (ntiles + 3) >> 2;

  kInit<<<512, 256, 0, stream>>>(cnt, cur, n, AdjU, ln_g, ln_b, w1, b1, Wg1, C0G1);
  kNode<<<1024, 256, 0, stream>>>(x, Wr, Wg1, C0G1, w2, b2, R, Ad, Crh, Srh, n);
  kCount<<<1024, 256, 0, stream>>>(ei, e, cnt, AdjU);
  kScan<<<1, 1024, 0, stream>>>(cnt, off, n);
  kPhaseFill<<<1024, 256, 0, stream>>>(ei, ew, e, R, Ad, C0G1, w2, b2, off, cur, recS, recCS);
  kScatter<<<2048, 256, 0, stream>>>(off, recS, recCS, R, Crh, Srh, n);
  kGcnExpm<<<1, 1024, 0, stream>>>(AdjU, g1w, g1b, g2w, g2b, aw1, ab1, aw2, ab2, aw3, ab3,
                                   Bg, UrT, UiT);
  kFinalM<<<fblocks, 256, 0, stream>>>(x, Crh, Srh, UrT, UiT, out, n, ntiles);
}

// Round 16
// 419.199 us; speedup vs baseline: 4.1283x; 1.6105x over previous
//
#include <hip/hip_runtime.h>
#include <hip/hip_bf16.h>
#include <hip/hip_fp16.h>

#define MAXPH 0.78539816339744831f
typedef unsigned short ushort_t;
typedef _Float16 half8 __attribute__((ext_vector_type(8)));
typedef float f32x4 __attribute__((ext_vector_type(4)));

__device__ __forceinline__ float wsum64(float v) {
#pragma unroll
  for (int o = 32; o > 0; o >>= 1) v += __shfl_xor(v, o);
  return v;
}
__device__ __forceinline__ float bf2f(ushort_t u) {
  return __uint_as_float(((unsigned)u) << 16);
}

// ---- kInit: zero cnt/cur/AdjU; last block also preps Wg1/C0G1
__global__ void kInit(unsigned* __restrict__ cnt, unsigned* __restrict__ cur, int n,
                      unsigned* __restrict__ AdjU,
                      const float* __restrict__ ln_g, const float* __restrict__ ln_b,
                      const float* __restrict__ w1, const float* __restrict__ b1,
                      float* __restrict__ Wg1, float* __restrict__ C0G1) {
  int t = blockIdx.x * blockDim.x + threadIdx.x;
  int st = gridDim.x * blockDim.x;
  for (int i = t; i < n; i += st) {
    cnt[i] = 0u;
    cur[i] = 0u;
  }
  for (int i = t; i < 4096; i += st) AdjU[i] = 0u;
  if (blockIdx.x == gridDim.x - 1) {
    int tt = threadIdx.x;
    for (int idx = tt; idx < 4096; idx += 256) {
      int j = idx >> 5;
      Wg1[idx] = ln_g[j] * w1[idx];
    }
    if (tt < 32) {
      float c0 = b1[tt], g1 = 0.f;
      for (int j = 0; j < 128; ++j) {
        float w = w1[j * 32 + tt];
        c0 = fmaf(ln_b[j], w, c0);
        g1 = fmaf(ln_g[j], w, g1);
      }
      C0G1[tt] = c0;
      C0G1[32 + tt] = g1;
    }
  }
}

// ---- kCount: per-dst-node histogram + masked AdjU build
__global__ void kCount(const int* __restrict__ ei, int ne, unsigned* __restrict__ cnt,
                       unsigned* __restrict__ AdjU) {
  int t = blockIdx.x * blockDim.x + threadIdx.x;
  int st = gridDim.x * blockDim.x;
  for (int e = t; e < ne; e += st) {
    int s = ei[e];
    int d = ei[ne + e];
    atomicAdd(&cnt[d], 1u);
    if ((unsigned)(s | d) < 64u) atomicAdd(&AdjU[d * 64 + s], 1u);
  }
}

// ---- kScan: exclusive prefix over n counters
__global__ __launch_bounds__(1024) void kScan(const unsigned* __restrict__ cnt,
                                              unsigned* __restrict__ off, int n) {
  __shared__ unsigned wsum[16];
  const int t = threadIdx.x;
  const int C = (n + 1023) >> 10;
  const int lo = t * C;
  const int hi = min(lo + C, n);
  unsigned s = 0;
  for (int i = lo; i < hi; ++i) s += cnt[i];
  unsigned v = s;
#pragma unroll
  for (int o = 1; o < 64; o <<= 1) {
    unsigned u = __shfl_up(v, o);
    if ((t & 63) >= o) v += u;
  }
  if ((t & 63) == 63) wsum[t >> 6] = v;
  __syncthreads();
  if (t == 0) {
    unsigned a = 0;
    for (int i = 0; i < 16; ++i) {
      unsigned c = wsum[i];
      wsum[i] = a;
      a += c;
    }
  }
  __syncthreads();
  unsigned run = wsum[t >> 6] + (v - s);
  for (int i = lo; i < hi; ++i) {
    off[i] = run;
    run += cnt[i];
  }
  if (t == 1023) off[n] = run;
}

// ---- kNodeM: MFMA node pipeline — LN -> h=LN(x)@Wr -> cm -> Ad/As=cm@Wg1 -> self-loop -> stores
__global__ __launch_bounds__(256) void kNodeM(
    const float* __restrict__ x, const float* __restrict__ Wr,
    const float* __restrict__ Wg1, const float* __restrict__ C0G1,
    const float* __restrict__ w2, const float* __restrict__ b2,
    ushort_t* __restrict__ R, __hip_bfloat16* __restrict__ Ad,
    __half* __restrict__ Crh, __half* __restrict__ Srh, int n, int ntiles) {
  __shared__ _Float16 bWr[512][8];   // slot = g*128 + c*64 + lane
  __shared__ _Float16 bAd[256][8];   // slot = g2*128 + c*64 + lane
  __shared__ _Float16 bAs[256][8];
  __shared__ _Float16 cmT[4][16][72];
  const int tid = threadIdx.x;
  const int lane = tid & 63;
  const int wave = tid >> 6;
  for (int slot = tid; slot < 512; slot += 256) {
    int g = slot >> 7;
    int c = (slot >> 6) & 1;
    int l = slot & 63;
    int col = g * 16 + (l & 15);
    int kb0 = c * 32 + ((l >> 4) << 3);
#pragma unroll
    for (int j = 0; j < 8; ++j) bWr[slot][j] = (_Float16)Wr[(kb0 + j) * 64 + col];
  }
  {
    int slot = tid;  // exactly 256 slots
    int g2 = slot >> 7;
    int c = (slot >> 6) & 1;
    int l = slot & 63;
    int col = g2 * 16 + (l & 15);
    int kb0 = c * 32 + ((l >> 4) << 3);
#pragma unroll
    for (int j = 0; j < 8; ++j) {
      bAd[slot][j] = (_Float16)Wg1[(kb0 + j) * 32 + col];
      bAs[slot][j] = (_Float16)Wg1[(64 + kb0 + j) * 32 + col];
    }
  }
  __syncthreads();
  const int tile = blockIdx.x * 4 + wave;
  if (tile >= ntiles) return;
  const int base = tile << 4;
  const int row = lane & 15;
  const int kb = (lane >> 4) << 3;
  const int nodeA = min(base + row, n - 1);
  const float* xp = x + (size_t)nodeA * 64;
  float xv[8], xh[8];
  *(float4*)&xv[0] = *(const float4*)(xp + kb);
  *(float4*)&xv[4] = *(const float4*)(xp + kb + 4);
  *(float4*)&xh[0] = *(const float4*)(xp + 32 + kb);
  *(float4*)&xh[4] = *(const float4*)(xp + 32 + kb + 4);
  float s1 = 0.f, s2 = 0.f;
#pragma unroll
  for (int j = 0; j < 8; ++j) {
    s1 += xv[j] + xh[j];
    s2 += xv[j] * xv[j] + xh[j] * xh[j];
  }
  s1 += __shfl_xor(s1, 16);
  s1 += __shfl_xor(s1, 32);
  s2 += __shfl_xor(s2, 16);
  s2 += __shfl_xor(s2, 32);
  float mean = s1 * 0.015625f;
  float var = fmaf(-mean, mean, s2 * 0.015625f);
  float rstd = rsqrtf(var + 1e-5f);
  half8 aLo, aHi;
#pragma unroll
  for (int j = 0; j < 8; ++j) {
    aLo[j] = (_Float16)((xv[j] - mean) * rstd);
    aHi[j] = (_Float16)((xh[j] - mean) * rstd);
  }
  f32x4 accH[4];
#pragma unroll
  for (int g = 0; g < 4; ++g) {
    f32x4 z4 = {0.f, 0.f, 0.f, 0.f};
    z4 = __builtin_amdgcn_mfma_f32_16x16x32_f16(aLo, *(const half8*)&bWr[g * 128 + lane][0], z4, 0, 0, 0);
    z4 = __builtin_amdgcn_mfma_f32_16x16x32_f16(aHi, *(const half8*)&bWr[g * 128 + 64 + lane][0], z4, 0, 0, 0);
    accH[g] = z4;
  }
  float cm[4][4];
  float p1[4] = {0.f, 0.f, 0.f, 0.f}, p2[4] = {0.f, 0.f, 0.f, 0.f};
#pragma unroll
  for (int g = 0; g < 4; ++g)
#pragma unroll
    for (int r = 0; r < 4; ++r) {
      float hv = accH[g][r];
      float m = fminf(sqrtf(fmaf(hv, hv, 1e-8f)), 10.f);
      cm[g][r] = m;
      p1[r] += m;
      p2[r] += m * m;
    }
#pragma unroll
  for (int o = 1; o <= 8; o <<= 1)
#pragma unroll
    for (int r = 0; r < 4; ++r) {
      p1[r] += __shfl_xor(p1[r], o);
      p2[r] += __shfl_xor(p2[r], o);
    }
  const int rgrp = (lane >> 4) << 2;
#pragma unroll
  for (int g = 0; g < 4; ++g)
#pragma unroll
    for (int r = 0; r < 4; ++r)
      cmT[wave][rgrp + r][g * 16 + (lane & 15)] = (_Float16)cm[g][r];
  half8 cLo = *(const half8*)&cmT[wave][row][kb];
  half8 cHi = *(const half8*)&cmT[wave][row][32 + kb];
  f32x4 accAd[2], accAs[2];
#pragma unroll
  for (int g2 = 0; g2 < 2; ++g2) {
    f32x4 z4 = {0.f, 0.f, 0.f, 0.f};
    z4 = __builtin_amdgcn_mfma_f32_16x16x32_f16(cLo, *(const half8*)&bAd[g2 * 128 + lane][0], z4, 0, 0, 0);
    z4 = __builtin_amdgcn_mfma_f32_16x16x32_f16(cHi, *(const half8*)&bAd[g2 * 128 + 64 + lane][0], z4, 0, 0, 0);
    accAd[g2] = z4;
    f32x4 w4 = {0.f, 0.f, 0.f, 0.f};
    w4 = __builtin_amdgcn_mfma_f32_16x16x32_f16(cLo, *(const half8*)&bAs[g2 * 128 + lane][0], w4, 0, 0, 0);
    w4 = __builtin_amdgcn_mfma_f32_16x16x32_f16(cHi, *(const half8*)&bAs[g2 * 128 + 64 + lane][0], w4, 0, 0, 0);
    accAs[g2] = w4;
  }
  const float b2r = b2[0];
  float c0v[2], g1v[2], w2v[2];
#pragma unroll
  for (int g2 = 0; g2 < 2; ++g2) {
    int k = g2 * 16 + (lane & 15);
    c0v[g2] = C0G1[k];
    g1v[g2] = C0G1[32 + k];
    w2v[g2] = w2[k];
  }
  float zp[4];
#pragma unroll
  for (int r = 0; r < 4; ++r) {
    float meanE = p1[r] * 0.015625f;
    float varE = fmaf(-meanE, meanE, p2[r] * 0.015625f);
    float rstdE = rsqrtf(varE + 1e-5f);
    float zz = 0.f;
#pragma unroll
    for (int g2 = 0; g2 < 2; ++g2) {
      float pre = fmaf(rstdE, fmaf(-meanE, g1v[g2], accAd[g2][r] + accAs[g2][r]), c0v[g2]);
      zz = fmaf(fmaxf(pre, 0.f), w2v[g2], zz);
    }
    zp[r] = zz;
  }
#pragma unroll
  for (int o = 1; o <= 8; o <<= 1)
#pragma unroll
    for (int r = 0; r < 4; ++r) zp[r] += __shfl_xor(zp[r], o);
  float csv[4], snv[4];
#pragma unroll
  for (int r = 0; r < 4; ++r) {
    float coup = 1.f / (1.f + expf(-(zp[r] + b2r)));
    float ph = fminf(0.3f * coup, MAXPH);
    sincosf(ph, &snv[r], &csv[r]);
  }
  const int colb = lane & 15;
#pragma unroll
  for (int r = 0; r < 4; ++r) {
    int node = base + rgrp + r;
    if (node >= n) break;
#pragma unroll
    for (int g = 0; g < 4; ++g) {
      int col = g * 16 + colb;
      float hv = accH[g][r];
      __hip_bfloat16 hb = __float2bfloat16(hv);
      R[(size_t)node * 128 + col] = *(ushort_t*)&hb;
      Crh[(size_t)node * 64 + col] = __float2half(hv * csv[r]);
      Srh[(size_t)node * 64 + col] = __float2half(hv * snv[r]);
    }
#pragma unroll
    for (int g2 = 0; g2 < 2; ++g2) {
      int col = g2 * 16 + colb;
      __hip_bfloat16 ab = __float2bfloat16(accAd[g2][r]);
      Ad[(size_t)node * 32 + col] = ab;
      __hip_bfloat16 sb2 = __float2bfloat16(accAs[g2][r]);
      R[(size_t)node * 128 + 64 + col] = *(ushort_t*)&sb2;
    }
    if (colb == 0) {
      float* sp = (float*)(R + (size_t)node * 128 + 96);
      sp[0] = p1[r];
      sp[1] = p2[r];
    }
  }
}

// ---- kPhaseFill: lane-per-edge phase compute, write {s,cos,sin} to dst-sorted slot
__global__ void kPhaseFill(const int* __restrict__ ei, const float* __restrict__ ew, int ne,
                           const ushort_t* __restrict__ R, const __hip_bfloat16* __restrict__ Ad,
                           const float* __restrict__ C0G1, const float* __restrict__ w2,
                           const float* __restrict__ b2,
                           const unsigned* __restrict__ off, unsigned* __restrict__ cur,
                           int* __restrict__ recS, float2* __restrict__ recCS) {
  const float b2r = b2[0];
  int t = blockIdx.x * blockDim.x + threadIdx.x;
  int st = gridDim.x * blockDim.x;
  for (int e = t; e < ne; e += st) {
    int s = ei[e];
    int d = ei[ne + e];
    const ushort_t* rs = R + (size_t)s * 128;
    const ushort_t* rd = R + (size_t)d * 128;
    float2 ps = *(const float2*)(rs + 96);
    float2 pd = *(const float2*)(rd + 96);
    float meanE = (ps.x + pd.x) * 0.0078125f;
    float varE = fmaf(-meanE, meanE, (ps.y + pd.y) * 0.0078125f);
    float rstdE = rsqrtf(varE + 1e-5f);
    const uint4* asq = (const uint4*)(rs + 64);
    const uint4* adq = (const uint4*)(Ad + (size_t)d * 32);
    float z = b2r;
#pragma unroll
    for (int q = 0; q < 4; ++q) {
      uint4 ua = adq[q];
      uint4 ub = asq[q];
      unsigned av[4] = {ua.x, ua.y, ua.z, ua.w};
      unsigned bv[4] = {ub.x, ub.y, ub.z, ub.w};
#pragma unroll
      for (int p = 0; p < 4; ++p) {
        int k0 = q * 8 + p * 2;
        float a0 = __uint_as_float(av[p] << 16);
        float a1 = __uint_as_float(av[p] & 0xFFFF0000u);
        float b0 = __uint_as_float(bv[p] << 16);
        float b1 = __uint_as_float(bv[p] & 0xFFFF0000u);
        float pre0 = fmaf(rstdE, fmaf(-meanE, C0G1[32 + k0], a0 + b0), C0G1[k0]);
        float pre1 = fmaf(rstdE, fmaf(-meanE, C0G1[32 + k0 + 1], a1 + b1), C0G1[k0 + 1]);
        z = fmaf(fmaxf(pre0, 0.f), w2[k0], z);
        z = fmaf(fmaxf(pre1, 0.f), w2[k0 + 1], z);
      }
    }
    float coup = 1.f / (1.f + expf(-z));
    float cw = fminf(fmaxf(ew[e], 0.1f), 2.f);
    float ph = fminf(0.3f * coup * cw, MAXPH);
    float sn, cs;
    sincosf(ph, &sn, &cs);
    unsigned p = atomicAdd(&cur[d], 1u);
    unsigned pos = off[d] + p;
    recS[pos] = s;
    recCS[pos] = make_float2(cs, sn);
  }
}

// ---- kScatter: wave-per-node register-accumulate gather
__global__ __launch_bounds__(256) void kScatter(
    const unsigned* __restrict__ off, const int* __restrict__ recS,
    const float2* __restrict__ recCS, const ushort_t* __restrict__ R,
    __half* __restrict__ Crh, __half* __restrict__ Srh, int n) {
  const int lane = threadIdx.x & 63;
  const int wid = (blockIdx.x * blockDim.x + threadIdx.x) >> 6;
  const int nw = (gridDim.x * blockDim.x) >> 6;
  for (int d = wid; d < n; d += nw) {
    unsigned u0 = off[d], u1 = off[d + 1];
    float accR = 0.f, accI = 0.f;
    unsigned j = u0;
    for (; j + 8 <= u1; j += 8) {
      int s8[8];
      float2 c8[8];
#pragma unroll
      for (int k = 0; k < 8; ++k) {
        s8[k] = recS[j + k];
        c8[k] = recCS[j + k];
      }
#pragma unroll
      for (int k = 0; k < 8; ++k) {
        float hv = bf2f(R[(size_t)s8[k] * 128 + lane]);
        accR = fmaf(hv, c8[k].x, accR);
        accI = fmaf(hv, c8[k].y, accI);
      }
    }
    for (; j < u1; ++j) {
      int s = recS[j];
      float2 c = recCS[j];
      float hv = bf2f(R[(size_t)s * 128 + lane]);
      accR = fmaf(hv, c.x, accR);
      accI = fmaf(hv, c.y, accI);
    }
    size_t idx = (size_t)d * 64 + lane;
    Crh[idx] = __float2half(__half2float(Crh[idx]) + accR);
    Srh[idx] = __float2half(__half2float(Srh[idx]) + accI);
  }
}

// ---- kGcnExpm: single block — AdjU (prebuilt) -> GCN x2 + pool + MLP + expm -> U^T
__global__ __launch_bounds__(1024) void kGcnExpm(
    const unsigned* __restrict__ AdjU,
    const float* __restrict__ g1w, const float* __restrict__ g1b,
    const float* __restrict__ g2w, const float* __restrict__ g2b,
    const float* __restrict__ aw1, const float* __restrict__ ab1,
    const float* __restrict__ aw2, const float* __restrict__ ab2,
    const float* __restrict__ aw3, const float* __restrict__ ab3,
    float* __restrict__ Bg, float* __restrict__ UrT, float* __restrict__ UiT) {
  __shared__ float SH[8192];
  __shared__ float sdv[64], sts[64], sgp[64], sz1[64], sz2[64];
  const int tid = threadIdx.x;
  for (int i = tid; i < 4096; i += 1024) SH[i] = (float)AdjU[i];
  __syncthreads();
  if (tid < 64) {
    float deg = 1.f;
    for (int s2 = 0; s2 < 64; ++s2) deg += SH[tid * 64 + s2];
    sdv[tid] = rsqrtf(deg);
  }
  __syncthreads();
  if (tid < 64) {
    float a = 0.f;
    for (int s2 = 0; s2 < 64; ++s2) a = fmaf(SH[tid * 64 + s2], sdv[s2], a);
    sts[tid] = a;
  }
  __syncthreads();
  float* h1 = SH + 4096;
  for (int idx = tid; idx < 4096; idx += 1024) {
    int d = idx >> 6, kk = idx & 63;
    h1[idx] = fmaxf(fmaf(g1w[kk], fmaf(sts[d], sdv[d], sdv[d] * sdv[d]), g1b[kk]), 0.f);
  }
  __syncthreads();
  const int i = tid >> 4, j0 = (tid & 15) << 2;
  float xw[4] = {0, 0, 0, 0};
  for (int m = 0; m < 64; ++m) {
    float hm = h1[i * 64 + m];
    const float* w = g2w + m * 64 + j0;
#pragma unroll
    for (int q = 0; q < 4; ++q) xw[q] = fmaf(hm, w[q], xw[q]);
  }
  __syncthreads();
#pragma unroll
  for (int q = 0; q < 4; ++q) h1[i * 64 + j0 + q] = xw[q];
  __syncthreads();
  {
    float a[4] = {0, 0, 0, 0};
    for (int s2 = 0; s2 < 64; ++s2) {
      float w = SH[i * 64 + s2] * sdv[s2];
      const float* xr = h1 + s2 * 64 + j0;
#pragma unroll
      for (int q = 0; q < 4; ++q) a[q] = fmaf(w, xr[q], a[q]);
    }
    float di = sdv[i], sc = di * di;
    float h2[4];
#pragma unroll
    for (int q = 0; q < 4; ++q)
      h2[q] = fmaf(a[q], di, fmaf(sc, h1[i * 64 + j0 + q], g2b[j0 + q]));
    __syncthreads();
#pragma unroll
    for (int q = 0; q < 4; ++q) h1[i * 64 + j0 + q] = h2[q];
  }
  __syncthreads();
  if (tid < 64) {
    float a = 0.f;
    for (int d = 0; d < 64; ++d) a += h1[d * 64 + tid];
    sgp[tid] = a * 0.015625f;
  }
  __syncthreads();
  if (tid < 64) {
    float a = ab1[tid];
    for (int m = 0; m < 64; ++m) a = fmaf(sgp[m], aw1[m * 64 + tid], a);
    sz1[tid] = fmaxf(a, 0.f);
  }
  __syncthreads();
  if (tid < 64) {
    float a = ab2[tid];
    for (int m = 0; m < 64; ++m) a = fmaf(sz1[m], aw2[m * 64 + tid], a);
    sz2[tid] = fmaxf(a, 0.f);
  }
  __syncthreads();
  for (int p4 = 0; p4 < 4; ++p4) {
    int rc = tid + p4 * 1024;
    float a = ab3[rc];
    for (int m = 0; m < 64; ++m) a = fmaf(sz2[m], aw3[m * 4096 + rc], a);
    SH[rc] = tanhf(a);
  }
  __syncthreads();
  const float SCC = 0.0015625f;  // 0.1*0.5/32
  for (int idx = tid; idx < 4096; idx += 1024) {
    int r = idx >> 6, c = idx & 63;
    float pr = SH[r * 64 + c], pt = SH[c * 64 + r];
    Bg[idx] = (pr - pt) * SCC;
    Bg[4096 + idx] = (pr + pt) * SCC;
  }
  __syncthreads();
  float* Xr = SH;
  float* Xi = SH + 4096;
  for (int idx = tid; idx < 4096; idx += 1024) {
    int r = idx >> 6, c = idx & 63;
    Xr[idx] = (r == c ? 1.f : 0.f) + Bg[idx] * (1.f / 6.f);
    Xi[idx] = Bg[4096 + idx] * (1.f / 6.f);
  }
  __syncthreads();
  for (int kk = 5; kk >= 1; --kk) {
    float ar[4] = {0, 0, 0, 0}, ai[4] = {0, 0, 0, 0};
    const float* brr = Bg + i * 64;
    const float* bir = Bg + 4096 + i * 64;
    for (int m = 0; m < 64; ++m) {
      float br = brr[m], bi = bir[m];
#pragma unroll
      for (int q = 0; q < 4; ++q) {
        float xr = Xr[m * 64 + j0 + q], xi = Xi[m * 64 + j0 + q];
        ar[q] = fmaf(br, xr, fmaf(-bi, xi, ar[q]));
        ai[q] = fmaf(br, xi, fmaf(bi, xr, ai[q]));
      }
    }
    __syncthreads();
    float inv = 1.f / (float)kk;
#pragma unroll
    for (int q = 0; q < 4; ++q) {
      int c = j0 + q;
      Xr[i * 64 + c] = (i == c ? 1.f : 0.f) + ar[q] * inv;
      Xi[i * 64 + c] = ai[q] * inv;
    }
    __syncthreads();
  }
  for (int sq = 0; sq < 5; ++sq) {
    float ar[4] = {0, 0, 0, 0}, ai[4] = {0, 0, 0, 0};
    for (int m = 0; m < 64; ++m) {
      float br = Xr[i * 64 + m], bi = Xi[i * 64 + m];
#pragma unroll
      for (int q = 0; q < 4; ++q) {
        float xr = Xr[m * 64 + j0 + q], xi = Xi[m * 64 + j0 + q];
        ar[q] = fmaf(br, xr, fmaf(-bi, xi, ar[q]));
        ai[q] = fmaf(br, xi, fmaf(bi, xr, ai[q]));
      }
    }
    __syncthreads();
#pragma unroll
    for (int q = 0; q < 4; ++q) {
      Xr[i * 64 + j0 + q] = ar[q];
      Xi[i * 64 + j0 + q] = ai[q];
    }
    __syncthreads();
  }
  for (int idx = tid; idx < 4096; idx += 1024) {
    int a2 = idx >> 6, b2i = idx & 63;
    UrT[idx] = Xr[b2i * 64 + a2];
    UiT[idx] = Xi[b2i * 64 + a2];
  }
}

// ---- kFinalM: MFMA GEMM — OutR=[Cr|Sr]@[UrT;-UiT], OutI=[Cr|Sr]@[UiT;UrT]; +0.5*LN(x)
__global__ __launch_bounds__(256) void kFinalM(
    const float* __restrict__ x, const __half* __restrict__ Crh,
    const __half* __restrict__ Srh, const float* __restrict__ UrT,
    const float* __restrict__ UiT, float* __restrict__ out, int n, int ntiles) {
  __shared__ _Float16 bR[1024][8];
  __shared__ _Float16 bI[1024][8];
  __shared__ float xrT[4][16][65];
  const int tid = threadIdx.x;
  const int lane = tid & 63;
  const int wave = tid >> 6;
  for (int slot = tid; slot < 1024; slot += 256) {
    int g = slot >> 8;
    int c = (slot >> 6) & 3;
    int l = slot & 63;
    int col = g * 16 + (l & 15);
    int kb = c * 32 + ((l >> 4) << 3);
#pragma unroll
    for (int j = 0; j < 8; ++j) {
      int k = kb + j;
      float vr, vi;
      if (k < 64) {
        vr = UrT[k * 64 + col];
        vi = UiT[k * 64 + col];
      } else {
        vr = -UiT[(k - 64) * 64 + col];
        vi = UrT[(k - 64) * 64 + col];
      }
      bR[slot][j] = (_Float16)vr;
      bI[slot][j] = (_Float16)vi;
    }
  }
  __syncthreads();
  const int tile = blockIdx.x * 4 + wave;
  if (tile >= ntiles) return;
  const int base = tile << 4;
  for (int nn = 0; nn < 16; ++nn) {
    int node = min(base + nn, n - 1);
    float xv = x[(size_t)node * 64 + lane];
    float s1 = wsum64(xv);
    float s2 = wsum64(xv * xv);
    float mean = s1 * 0.015625f;
    float var = fmaf(-mean, mean, s2 * 0.015625f);
    xrT[wave][nn][lane] = (xv - mean) * rsqrtf(var + 1e-5f);
  }
  const int row = lane & 15;
  const int node = min(base + row, n - 1);
  const int kb = (lane >> 4) << 3;
  const _Float16* crp = (const _Float16*)(Crh + (size_t)node * 64);
  const _Float16* srp = (const _Float16*)(Srh + (size_t)node * 64);
  half8 a0 = *(const half8*)(crp + kb);
  half8 a1 = *(const half8*)(crp + 32 + kb);
  half8 a2 = *(const half8*)(srp + kb);
  half8 a3 = *(const half8*)(srp + 32 + kb);
  const size_t imag_off = (size_t)n * 64;
  const int rgrp = (lane >> 4) << 2;
#pragma unroll
  for (int g = 0; g < 4; ++g) {
    f32x4 accR = {0.f, 0.f, 0.f, 0.f};
    f32x4 accI = {0.f, 0.f, 0.f, 0.f};
    const int sb = g * 256 + lane;
    half8 br0 = *(const half8*)&bR[sb][0];
    half8 br1 = *(const half8*)&bR[sb + 64][0];
    half8 br2 = *(const half8*)&bR[sb + 128][0];
    half8 br3 = *(const half8*)&bR[sb + 192][0];
    accR = __builtin_amdgcn_mfma_f32_16x16x32_f16(a0, br0, accR, 0, 0, 0);
    accR = __builtin_amdgcn_mfma_f32_16x16x32_f16(a1, br1, accR, 0, 0, 0);
    accR = __builtin_amdgcn_mfma_f32_16x16x32_f16(a2, br2, accR, 0, 0, 0);
    accR = __builtin_amdgcn_mfma_f32_16x16x32_f16(a3, br3, accR, 0, 0, 0);
    half8 bi0 = *(const half8*)&bI[sb][0];
    half8 bi1 = *(const half8*)&bI[sb + 64][0];
    half8 bi2 = *(const half8*)&bI[sb + 128][0];
    half8 bi3 = *(const half8*)&bI[sb + 192][0];
    accI = __builtin_amdgcn_mfma_f32_16x16x32_f16(a0, bi0, accI, 0, 0, 0);
    accI = __builtin_amdgcn_mfma_f32_16x16x32_f16(a1, bi1, accI, 0, 0, 0);
    accI = __builtin_amdgcn_mfma_f32_16x16x32_f16(a2, bi2, accI, 0, 0, 0);
    accI = __builtin_amdgcn_mfma_f32_16x16x32_f16(a3, bi3, accI, 0, 0, 0);
    const int col = g * 16 + (lane & 15);
#pragma unroll
    for (int reg = 0; reg < 4; ++reg) {
      int r = base + rgrp + reg;
      if (r < n) {
        out[(size_t)r * 64 + col] = 0.5f * (accR[reg] + xrT[wave][rgrp + reg][col]);
        out[imag_off + (size_t)r * 64 + col] = 0.5f * accI[reg];
      }
    }
  }
}

extern "C" void kernel_launch(void* const* d_in, const int* in_sizes, int n_in,
                              void* d_out, int out_size, void* d_ws, size_t ws_size,
                              hipStream_t stream) {
  const float* x    = (const float*)d_in[0];
  const int*   ei   = (const int*)d_in[1];
  const float* ew   = (const float*)d_in[2];
  const float* Wr   = (const float*)d_in[3];
  const float* ln_g = (const float*)d_in[5];
  const float* ln_b = (const float*)d_in[6];
  const float* w1   = (const float*)d_in[7];
  const float* b1   = (const float*)d_in[8];
  const float* w2   = (const float*)d_in[9];
  const float* b2   = (const float*)d_in[10];
  const float* g1w  = (const float*)d_in[11];
  const float* g1b  = (const float*)d_in[12];
  const float* g2w  = (const float*)d_in[13];
  const float* g2b  = (const float*)d_in[14];
  const float* aw1  = (const float*)d_in[15];
  const float* ab1  = (const float*)d_in[16];
  const float* aw2  = (const float*)d_in[17];
  const float* ab2  = (const float*)d_in[18];
  const float* aw3  = (const float*)d_in[19];
  const float* ab3  = (const float*)d_in[20];
  const int n = in_sizes[0] / 64;
  const int e = in_sizes[1] / 2;
  float* out = (float*)d_out;

  float* ws = (float*)d_ws;
  float* Wg1  = ws;                           // 4096
  float* C0G1 = ws + 4096;                    // 64
  float* UrT  = ws + 4160;                    // 4096
  float* UiT  = ws + 8256;                    // 4096
  float* Bg   = ws + 12352;                   // 8192
  unsigned* AdjU = (unsigned*)(ws + 20544);   // 4096 u32
  unsigned* cnt = AdjU + 4096;                // n
  unsigned* off = cnt + n;                    // n+1
  unsigned* cur = off + n + 1;                // n
  size_t p0 = (20544 + 4096 + 3 * (size_t)n + 1 + 63) & ~(size_t)63;
  int* recS = (int*)(ws + p0);                // e
  size_t p1 = (p0 + (size_t)e + 63) & ~(size_t)63;
  float2* recCS = (float2*)(ws + p1);         // 2e
  size_t p2 = (p1 + 2 * (size_t)e + 63) & ~(size_t)63;
  ushort_t* R = (ushort_t*)(ws + p2);         // 64n f32-units
  size_t p3 = (p2 + 64 * (size_t)n + 63) & ~(size_t)63;
  __hip_bfloat16* Ad = (__hip_bfloat16*)(ws + p3);  // 16n
  size_t p4 = (p3 + 16 * (size_t)n + 63) & ~(size_t)63;
  __half* Crh = (__half*)(ws + p4);           // 32n
  size_t p5 = (p4 + 32 * (size_t)n + 63) & ~(size_t)63;
  __half* Srh = (__half*)(ws + p5);           // 32n

  const int ntiles = (n + 15) >> 4;
  const int fblocks = (ntiles + 3) >> 2;

  kInit<<<512, 256, 0, stream>>>(cnt, cur, n, AdjU, ln_g, ln_b, w1, b1, Wg1, C0G1);
  kNodeM<<<fblocks, 256, 0, stream>>>(x, Wr, Wg1, C0G1, w2, b2, R, Ad, Crh, Srh, n, ntiles);
  kCount<<<1024, 256, 0, stream>>>(ei, e, cnt, AdjU);
  kScan<<<1, 1024, 0, stream>>>(cnt, off, n);
  kPhaseFill<<<1024, 256, 0, stream>>>(ei, ew, e, R, Ad, C0G1, w2, b2, off, cur, recS, recCS);
  kScatter<<<2048, 256, 0, stream>>>(off, recS, recCS, R, Crh, Srh, n);
  kGcnExpm<<<1, 1024, 0, stream>>>(AdjU, g1w, g1b, g2w, g2b, aw1, ab1, aw2, ab2, aw3, ab3,
                                   Bg, UrT, UiT);
  kFinalM<<<fblocks, 256, 0, stream>>>(x, Crh, Srh, UrT, UiT, out, n, ntiles);
}

// Round 17
// 374.353 us; speedup vs baseline: 4.6228x; 1.1198x over previous
//
#include <hip/hip_runtime.h>
#include <hip/hip_bf16.h>
#include <hip/hip_fp16.h>

#define MAXPH 0.78539816339744831f
typedef unsigned short ushort_t;
typedef _Float16 half8 __attribute__((ext_vector_type(8)));
typedef float f32x4 __attribute__((ext_vector_type(4)));

__device__ __forceinline__ float wsum64(float v) {
#pragma unroll
  for (int o = 32; o > 0; o >>= 1) v += __shfl_xor(v, o);
  return v;
}
__device__ __forceinline__ float bf2f(ushort_t u) {
  return __uint_as_float(((unsigned)u) << 16);
}

// ---- kInit: zero cnt/cur/AdjU; last block also preps Wg1/C0G1
__global__ void kInit(unsigned* __restrict__ cnt, unsigned* __restrict__ cur, int n,
                      unsigned* __restrict__ AdjU,
                      const float* __restrict__ ln_g, const float* __restrict__ ln_b,
                      const float* __restrict__ w1, const float* __restrict__ b1,
                      float* __restrict__ Wg1, float* __restrict__ C0G1) {
  int t = blockIdx.x * blockDim.x + threadIdx.x;
  int st = gridDim.x * blockDim.x;
  for (int i = t; i < n; i += st) {
    cnt[i] = 0u;
    cur[i] = 0u;
  }
  for (int i = t; i < 4096; i += st) AdjU[i] = 0u;
  if (blockIdx.x == gridDim.x - 1) {
    int tt = threadIdx.x;
    for (int idx = tt; idx < 4096; idx += 256) {
      int j = idx >> 5;
      Wg1[idx] = ln_g[j] * w1[idx];
    }
    if (tt < 32) {
      float c0 = b1[tt], g1 = 0.f;
      for (int j = 0; j < 128; ++j) {
        float w = w1[j * 32 + tt];
        c0 = fmaf(ln_b[j], w, c0);
        g1 = fmaf(ln_g[j], w, g1);
      }
      C0G1[tt] = c0;
      C0G1[32 + tt] = g1;
    }
  }
}

// ---- kCount: per-dst-node histogram + masked AdjU build
__global__ void kCount(const int* __restrict__ ei, int ne, unsigned* __restrict__ cnt,
                       unsigned* __restrict__ AdjU) {
  int t = blockIdx.x * blockDim.x + threadIdx.x;
  int st = gridDim.x * blockDim.x;
  for (int e = t; e < ne; e += st) {
    int s = ei[e];
    int d = ei[ne + e];
    atomicAdd(&cnt[d], 1u);
    if ((unsigned)(s | d) < 64u) atomicAdd(&AdjU[d * 64 + s], 1u);
  }
}

// ---- kScan: exclusive prefix over n counters
__global__ __launch_bounds__(1024) void kScan(const unsigned* __restrict__ cnt,
                                              unsigned* __restrict__ off, int n) {
  __shared__ unsigned wsum[16];
  const int t = threadIdx.x;
  const int C = (n + 1023) >> 10;
  const int lo = t * C;
  const int hi = min(lo + C, n);
  unsigned s = 0;
  for (int i = lo; i < hi; ++i) s += cnt[i];
  unsigned v = s;
#pragma unroll
  for (int o = 1; o < 64; o <<= 1) {
    unsigned u = __shfl_up(v, o);
    if ((t & 63) >= o) v += u;
  }
  if ((t & 63) == 63) wsum[t >> 6] = v;
  __syncthreads();
  if (t == 0) {
    unsigned a = 0;
    for (int i = 0; i < 16; ++i) {
      unsigned c = wsum[i];
      wsum[i] = a;
      a += c;
    }
  }
  __syncthreads();
  unsigned run = wsum[t >> 6] + (v - s);
  for (int i = lo; i < hi; ++i) {
    off[i] = run;
    run += cnt[i];
  }
  if (t == 1023) off[n] = run;
}

// ---- kNodeM: MFMA node pipeline
__global__ __launch_bounds__(256) void kNodeM(
    const float* __restrict__ x, const float* __restrict__ Wr,
    const float* __restrict__ Wg1, const float* __restrict__ C0G1,
    const float* __restrict__ w2, const float* __restrict__ b2,
    ushort_t* __restrict__ R, __hip_bfloat16* __restrict__ Ad,
    __half* __restrict__ Crh, __half* __restrict__ Srh, int n, int ntiles) {
  __shared__ _Float16 bWr[512][8];
  __shared__ _Float16 bAd[256][8];
  __shared__ _Float16 bAs[256][8];
  __shared__ _Float16 cmT[4][16][72];
  const int tid = threadIdx.x;
  const int lane = tid & 63;
  const int wave = tid >> 6;
  for (int slot = tid; slot < 512; slot += 256) {
    int g = slot >> 7;
    int c = (slot >> 6) & 1;
    int l = slot & 63;
    int col = g * 16 + (l & 15);
    int kb0 = c * 32 + ((l >> 4) << 3);
#pragma unroll
    for (int j = 0; j < 8; ++j) bWr[slot][j] = (_Float16)Wr[(kb0 + j) * 64 + col];
  }
  {
    int slot = tid;
    int g2 = slot >> 7;
    int c = (slot >> 6) & 1;
    int l = slot & 63;
    int col = g2 * 16 + (l & 15);
    int kb0 = c * 32 + ((l >> 4) << 3);
#pragma unroll
    for (int j = 0; j < 8; ++j) {
      bAd[slot][j] = (_Float16)Wg1[(kb0 + j) * 32 + col];
      bAs[slot][j] = (_Float16)Wg1[(64 + kb0 + j) * 32 + col];
    }
  }
  __syncthreads();
  const int tile = blockIdx.x * 4 + wave;
  if (tile >= ntiles) return;
  const int base = tile << 4;
  const int row = lane & 15;
  const int kb = (lane >> 4) << 3;
  const int nodeA = min(base + row, n - 1);
  const float* xp = x + (size_t)nodeA * 64;
  float xv[8], xh[8];
  *(float4*)&xv[0] = *(const float4*)(xp + kb);
  *(float4*)&xv[4] = *(const float4*)(xp + kb + 4);
  *(float4*)&xh[0] = *(const float4*)(xp + 32 + kb);
  *(float4*)&xh[4] = *(const float4*)(xp + 32 + kb + 4);
  float s1 = 0.f, s2 = 0.f;
#pragma unroll
  for (int j = 0; j < 8; ++j) {
    s1 += xv[j] + xh[j];
    s2 += xv[j] * xv[j] + xh[j] * xh[j];
  }
  s1 += __shfl_xor(s1, 16);
  s1 += __shfl_xor(s1, 32);
  s2 += __shfl_xor(s2, 16);
  s2 += __shfl_xor(s2, 32);
  float mean = s1 * 0.015625f;
  float var = fmaf(-mean, mean, s2 * 0.015625f);
  float rstd = rsqrtf(var + 1e-5f);
  half8 aLo, aHi;
#pragma unroll
  for (int j = 0; j < 8; ++j) {
    aLo[j] = (_Float16)((xv[j] - mean) * rstd);
    aHi[j] = (_Float16)((xh[j] - mean) * rstd);
  }
  f32x4 accH[4];
#pragma unroll
  for (int g = 0; g < 4; ++g) {
    f32x4 z4 = {0.f, 0.f, 0.f, 0.f};
    z4 = __builtin_amdgcn_mfma_f32_16x16x32_f16(aLo, *(const half8*)&bWr[g * 128 + lane][0], z4, 0, 0, 0);
    z4 = __builtin_amdgcn_mfma_f32_16x16x32_f16(aHi, *(const half8*)&bWr[g * 128 + 64 + lane][0], z4, 0, 0, 0);
    accH[g] = z4;
  }
  float cm[4][4];
  float p1[4] = {0.f, 0.f, 0.f, 0.f}, p2[4] = {0.f, 0.f, 0.f, 0.f};
#pragma unroll
  for (int g = 0; g < 4; ++g)
#pragma unroll
    for (int r = 0; r < 4; ++r) {
      float hv = accH[g][r];
      float m = fminf(sqrtf(fmaf(hv, hv, 1e-8f)), 10.f);
      cm[g][r] = m;
      p1[r] += m;
      p2[r] += m * m;
    }
#pragma unroll
  for (int o = 1; o <= 8; o <<= 1)
#pragma unroll
    for (int r = 0; r < 4; ++r) {
      p1[r] += __shfl_xor(p1[r], o);
      p2[r] += __shfl_xor(p2[r], o);
    }
  const int rgrp = (lane >> 4) << 2;
#pragma unroll
  for (int g = 0; g < 4; ++g)
#pragma unroll
    for (int r = 0; r < 4; ++r)
      cmT[wave][rgrp + r][g * 16 + (lane & 15)] = (_Float16)cm[g][r];
  half8 cLo = *(const half8*)&cmT[wave][row][kb];
  half8 cHi = *(const half8*)&cmT[wave][row][32 + kb];
  f32x4 accAd[2], accAs[2];
#pragma unroll
  for (int g2 = 0; g2 < 2; ++g2) {
    f32x4 z4 = {0.f, 0.f, 0.f, 0.f};
    z4 = __builtin_amdgcn_mfma_f32_16x16x32_f16(cLo, *(const half8*)&bAd[g2 * 128 + lane][0], z4, 0, 0, 0);
    z4 = __builtin_amdgcn_mfma_f32_16x16x32_f16(cHi, *(const half8*)&bAd[g2 * 128 + 64 + lane][0], z4, 0, 0, 0);
    accAd[g2] = z4;
    f32x4 w4 = {0.f, 0.f, 0.f, 0.f};
    w4 = __builtin_amdgcn_mfma_f32_16x16x32_f16(cLo, *(const half8*)&bAs[g2 * 128 + lane][0], w4, 0, 0, 0);
    w4 = __builtin_amdgcn_mfma_f32_16x16x32_f16(cHi, *(const half8*)&bAs[g2 * 128 + 64 + lane][0], w4, 0, 0, 0);
    accAs[g2] = w4;
  }
  const float b2r = b2[0];
  float c0v[2], g1v[2], w2v[2];
#pragma unroll
  for (int g2 = 0; g2 < 2; ++g2) {
    int k = g2 * 16 + (lane & 15);
    c0v[g2] = C0G1[k];
    g1v[g2] = C0G1[32 + k];
    w2v[g2] = w2[k];
  }
  float zp[4];
#pragma unroll
  for (int r = 0; r < 4; ++r) {
    float meanE = p1[r] * 0.015625f;
    float varE = fmaf(-meanE, meanE, p2[r] * 0.015625f);
    float rstdE = rsqrtf(varE + 1e-5f);
    float zz = 0.f;
#pragma unroll
    for (int g2 = 0; g2 < 2; ++g2) {
      float pre = fmaf(rstdE, fmaf(-meanE, g1v[g2], accAd[g2][r] + accAs[g2][r]), c0v[g2]);
      zz = fmaf(fmaxf(pre, 0.f), w2v[g2], zz);
    }
    zp[r] = zz;
  }
#pragma unroll
  for (int o = 1; o <= 8; o <<= 1)
#pragma unroll
    for (int r = 0; r < 4; ++r) zp[r] += __shfl_xor(zp[r], o);
  float csv[4], snv[4];
#pragma unroll
  for (int r = 0; r < 4; ++r) {
    float coup = 1.f / (1.f + expf(-(zp[r] + b2r)));
    float ph = fminf(0.3f * coup, MAXPH);
    sincosf(ph, &snv[r], &csv[r]);
  }
  const int colb = lane & 15;
#pragma unroll
  for (int r = 0; r < 4; ++r) {
    int node = base + rgrp + r;
    if (node >= n) break;
#pragma unroll
    for (int g = 0; g < 4; ++g) {
      int col = g * 16 + colb;
      float hv = accH[g][r];
      __hip_bfloat16 hb = __float2bfloat16(hv);
      R[(size_t)node * 128 + col] = *(ushort_t*)&hb;
      Crh[(size_t)node * 64 + col] = __float2half(hv * csv[r]);
      Srh[(size_t)node * 64 + col] = __float2half(hv * snv[r]);
    }
#pragma unroll
    for (int g2 = 0; g2 < 2; ++g2) {
      int col = g2 * 16 + colb;
      __hip_bfloat16 ab = __float2bfloat16(accAd[g2][r]);
      Ad[(size_t)node * 32 + col] = ab;
      __hip_bfloat16 sb2 = __float2bfloat16(accAs[g2][r]);
      R[(size_t)node * 128 + 64 + col] = *(ushort_t*)&sb2;
    }
    if (colb == 0) {
      float* sp = (float*)(R + (size_t)node * 128 + 96);
      sp[0] = p1[r];
      sp[1] = p2[r];
    }
  }
}

// ---- kPhaseFill: lane-per-edge phase compute -> dst-sorted slot
__global__ void kPhaseFill(const int* __restrict__ ei, const float* __restrict__ ew, int ne,
                           const ushort_t* __restrict__ R, const __hip_bfloat16* __restrict__ Ad,
                           const float* __restrict__ C0G1, const float* __restrict__ w2,
                           const float* __restrict__ b2,
                           const unsigned* __restrict__ off, unsigned* __restrict__ cur,
                           int* __restrict__ recS, float2* __restrict__ recCS) {
  const float b2r = b2[0];
  int t = blockIdx.x * blockDim.x + threadIdx.x;
  int st = gridDim.x * blockDim.x;
  for (int e = t; e < ne; e += st) {
    int s = ei[e];
    int d = ei[ne + e];
    const ushort_t* rs = R + (size_t)s * 128;
    const ushort_t* rd = R + (size_t)d * 128;
    float2 ps = *(const float2*)(rs + 96);
    float2 pd = *(const float2*)(rd + 96);
    float meanE = (ps.x + pd.x) * 0.0078125f;
    float varE = fmaf(-meanE, meanE, (ps.y + pd.y) * 0.0078125f);
    float rstdE = rsqrtf(varE + 1e-5f);
    const uint4* asq = (const uint4*)(rs + 64);
    const uint4* adq = (const uint4*)(Ad + (size_t)d * 32);
    float z = b2r;
#pragma unroll
    for (int q = 0; q < 4; ++q) {
      uint4 ua = adq[q];
      uint4 ub = asq[q];
      unsigned av[4] = {ua.x, ua.y, ua.z, ua.w};
      unsigned bv[4] = {ub.x, ub.y, ub.z, ub.w};
#pragma unroll
      for (int p = 0; p < 4; ++p) {
        int k0 = q * 8 + p * 2;
        float a0 = __uint_as_float(av[p] << 16);
        float a1 = __uint_as_float(av[p] & 0xFFFF0000u);
        float b0 = __uint_as_float(bv[p] << 16);
        float b1 = __uint_as_float(bv[p] & 0xFFFF0000u);
        float pre0 = fmaf(rstdE, fmaf(-meanE, C0G1[32 + k0], a0 + b0), C0G1[k0]);
        float pre1 = fmaf(rstdE, fmaf(-meanE, C0G1[32 + k0 + 1], a1 + b1), C0G1[k0 + 1]);
        z = fmaf(fmaxf(pre0, 0.f), w2[k0], z);
        z = fmaf(fmaxf(pre1, 0.f), w2[k0 + 1], z);
      }
    }
    float coup = 1.f / (1.f + expf(-z));
    float cw = fminf(fmaxf(ew[e], 0.1f), 2.f);
    float ph = fminf(0.3f * coup * cw, MAXPH);
    float sn, cs;
    sincosf(ph, &sn, &cs);
    unsigned p = atomicAdd(&cur[d], 1u);
    unsigned pos = off[d] + p;
    recS[pos] = s;
    recCS[pos] = make_float2(cs, sn);
  }
}

// ---- kScatter: wave-per-node register-accumulate gather
__global__ __launch_bounds__(256) void kScatter(
    const unsigned* __restrict__ off, const int* __restrict__ recS,
    const float2* __restrict__ recCS, const ushort_t* __restrict__ R,
    __half* __restrict__ Crh, __half* __restrict__ Srh, int n) {
  const int lane = threadIdx.x & 63;
  const int wid = (blockIdx.x * blockDim.x + threadIdx.x) >> 6;
  const int nw = (gridDim.x * blockDim.x) >> 6;
  for (int d = wid; d < n; d += nw) {
    unsigned u0 = off[d], u1 = off[d + 1];
    float accR = 0.f, accI = 0.f;
    unsigned j = u0;
    for (; j + 8 <= u1; j += 8) {
      int s8[8];
      float2 c8[8];
#pragma unroll
      for (int k = 0; k < 8; ++k) {
        s8[k] = recS[j + k];
        c8[k] = recCS[j + k];
      }
#pragma unroll
      for (int k = 0; k < 8; ++k) {
        float hv = bf2f(R[(size_t)s8[k] * 128 + lane]);
        accR = fmaf(hv, c8[k].x, accR);
        accI = fmaf(hv, c8[k].y, accI);
      }
    }
    for (; j < u1; ++j) {
      int s = recS[j];
      float2 c = recCS[j];
      float hv = bf2f(R[(size_t)s * 128 + lane]);
      accR = fmaf(hv, c.x, accR);
      accI = fmaf(hv, c.y, accI);
    }
    size_t idx = (size_t)d * 64 + lane;
    Crh[idx] = __float2half(__half2float(Crh[idx]) + accR);
    Srh[idx] = __float2half(__half2float(Srh[idx]) + accI);
  }
}

// ---- kGcnMlp: single block — AdjU -> GCN x2 + pool + MLP -> z2 (padded LDS, no conflicts)
__global__ __launch_bounds__(1024) void kGcnMlp(
    const unsigned* __restrict__ AdjU,
    const float* __restrict__ g1w, const float* __restrict__ g1b,
    const float* __restrict__ g2w, const float* __restrict__ g2b,
    const float* __restrict__ aw1, const float* __restrict__ ab1,
    const float* __restrict__ aw2, const float* __restrict__ ab2,
    float* __restrict__ z2g) {
  __shared__ float L0[64 * 65];
  __shared__ float L1[64 * 65];
  __shared__ float sdv[64], sts[64], sgp[64], sz1[64];
  const int tid = threadIdx.x;
  for (int idx = tid; idx < 4096; idx += 1024) {
    int r = idx >> 6, c = idx & 63;
    L0[r * 65 + c] = (float)AdjU[idx];
  }
  __syncthreads();
  if (tid < 64) {
    float deg = 1.f;
    for (int s2 = 0; s2 < 64; ++s2) deg += L0[tid * 65 + s2];
    sdv[tid] = rsqrtf(deg);
  }
  __syncthreads();
  if (tid < 64) {
    float a = 0.f;
    for (int s2 = 0; s2 < 64; ++s2) a = fmaf(L0[tid * 65 + s2], sdv[s2], a);
    sts[tid] = a;
  }
  __syncthreads();
  for (int idx = tid; idx < 4096; idx += 1024) {
    int d = idx >> 6, kk = idx & 63;
    L1[d * 65 + kk] = fmaxf(fmaf(g1w[kk], fmaf(sts[d], sdv[d], sdv[d] * sdv[d]), g1b[kk]), 0.f);
  }
  __syncthreads();
  const int i = tid >> 4, j0 = (tid & 15) << 2;
  float xw[4] = {0, 0, 0, 0};
  for (int m = 0; m < 64; ++m) {
    float hm = L1[i * 65 + m];
    const float* w = g2w + m * 64 + j0;
#pragma unroll
    for (int q = 0; q < 4; ++q) xw[q] = fmaf(hm, w[q], xw[q]);
  }
  __syncthreads();
#pragma unroll
  for (int q = 0; q < 4; ++q) L1[i * 65 + j0 + q] = xw[q];
  __syncthreads();
  {
    float a[4] = {0, 0, 0, 0};
    for (int s2 = 0; s2 < 64; ++s2) {
      float w = L0[i * 65 + s2] * sdv[s2];
#pragma unroll
      for (int q = 0; q < 4; ++q) a[q] = fmaf(w, L1[s2 * 65 + j0 + q], a[q]);
    }
    float di = sdv[i], sc = di * di;
    float h2[4];
#pragma unroll
    for (int q = 0; q < 4; ++q)
      h2[q] = fmaf(a[q], di, fmaf(sc, L1[i * 65 + j0 + q], g2b[j0 + q]));
    __syncthreads();
#pragma unroll
    for (int q = 0; q < 4; ++q) L1[i * 65 + j0 + q] = h2[q];
  }
  __syncthreads();
  if (tid < 64) {
    float a = 0.f;
    for (int d = 0; d < 64; ++d) a += L1[d * 65 + tid];
    sgp[tid] = a * 0.015625f;
  }
  __syncthreads();
  if (tid < 64) {
    float a = ab1[tid];
    for (int m = 0; m < 64; ++m) a = fmaf(sgp[m], aw1[m * 64 + tid], a);
    sz1[tid] = fmaxf(a, 0.f);
  }
  __syncthreads();
  if (tid < 64) {
    float a = ab2[tid];
    for (int m = 0; m < 64; ++m) a = fmaf(sz1[m], aw2[m * 64 + tid], a);
    z2g[tid] = fmaxf(a, 0.f);
  }
}

// ---- kTanh: wide — p = tanh(z2@aw3 + ab3)
__global__ __launch_bounds__(256) void kTanh(const float* __restrict__ z2g,
                                             const float* __restrict__ aw3,
                                             const float* __restrict__ ab3,
                                             float* __restrict__ pG) {
  int rc = blockIdx.x * 256 + threadIdx.x;
  float a = ab3[rc];
  for (int m = 0; m < 64; ++m) a = fmaf(z2g[m], aw3[m * 4096 + rc], a);
  pG[rc] = tanhf(a);
}

// ---- kExpm: single block — B from p (padded LDS), Taylor-6 Horner + 5 squarings -> U^T
__global__ __launch_bounds__(1024) void kExpm(const float* __restrict__ pG,
                                              float* __restrict__ UrT,
                                              float* __restrict__ UiT) {
  __shared__ float Br[64 * 65], Bi[64 * 65];
  __shared__ float Xr[64 * 68], Xi[64 * 68];
  const int tid = threadIdx.x;
  const float SCC = 0.0015625f;  // 0.1*0.5/32
  for (int idx = tid; idx < 4096; idx += 1024) {
    int r = idx >> 6, c = idx & 63;
    float pr = pG[r * 64 + c], pt = pG[c * 64 + r];
    float br = (pr - pt) * SCC;
    float bi = (pr + pt) * SCC;
    Br[r * 65 + c] = br;
    Bi[r * 65 + c] = bi;
    Xr[r * 68 + c] = (r == c ? 1.f : 0.f) + br * (1.f / 6.f);
    Xi[r * 68 + c] = bi * (1.f / 6.f);
  }
  __syncthreads();
  const int i = tid >> 4, j0 = (tid & 15) << 2;
  for (int kk = 5; kk >= 1; --kk) {
    float ar[4] = {0, 0, 0, 0}, ai[4] = {0, 0, 0, 0};
    for (int m = 0; m < 64; ++m) {
      float br = Br[i * 65 + m], bi = Bi[i * 65 + m];
      float4 xr4 = *(const float4*)&Xr[m * 68 + j0];
      float4 xi4 = *(const float4*)&Xi[m * 68 + j0];
      float xr[4] = {xr4.x, xr4.y, xr4.z, xr4.w};
      float xi[4] = {xi4.x, xi4.y, xi4.z, xi4.w};
#pragma unroll
      for (int q = 0; q < 4; ++q) {
        ar[q] = fmaf(br, xr[q], fmaf(-bi, xi[q], ar[q]));
        ai[q] = fmaf(br, xi[q], fmaf(bi, xr[q], ai[q]));
      }
    }
    __syncthreads();
    float inv = 1.f / (float)kk;
#pragma unroll
    for (int q = 0; q < 4; ++q) {
      int c = j0 + q;
      Xr[i * 68 + c] = (i == c ? 1.f : 0.f) + ar[q] * inv;
      Xi[i * 68 + c] = ai[q] * inv;
    }
    __syncthreads();
  }
  for (int sq = 0; sq < 5; ++sq) {
    float ar[4] = {0, 0, 0, 0}, ai[4] = {0, 0, 0, 0};
    for (int m = 0; m < 64; ++m) {
      float br = Xr[i * 68 + m], bi = Xi[i * 68 + m];
      float4 xr4 = *(const float4*)&Xr[m * 68 + j0];
      float4 xi4 = *(const float4*)&Xi[m * 68 + j0];
      float xr[4] = {xr4.x, xr4.y, xr4.z, xr4.w};
      float xi[4] = {xi4.x, xi4.y, xi4.z, xi4.w};
#pragma unroll
      for (int q = 0; q < 4; ++q) {
        ar[q] = fmaf(br, xr[q], fmaf(-bi, xi[q], ar[q]));
        ai[q] = fmaf(br, xi[q], fmaf(bi, xr[q], ai[q]));
      }
    }
    __syncthreads();
#pragma unroll
    for (int q = 0; q < 4; ++q) {
      Xr[i * 68 + j0 + q] = ar[q];
      Xi[i * 68 + j0 + q] = ai[q];
    }
    __syncthreads();
  }
  for (int idx = tid; idx < 4096; idx += 1024) {
    int a2 = idx >> 6, b2i = idx & 63;
    UrT[idx] = Xr[b2i * 68 + a2];
    UiT[idx] = Xi[b2i * 68 + a2];
  }
}

// ---- kFinalM: MFMA GEMM — OutR=[Cr|Sr]@[UrT;-UiT], OutI=[Cr|Sr]@[UiT;UrT]; +0.5*LN(x)
__global__ __launch_bounds__(256) void kFinalM(
    const float* __restrict__ x, const __half* __restrict__ Crh,
    const __half* __restrict__ Srh, const float* __restrict__ UrT,
    const float* __restrict__ UiT, float* __restrict__ out, int n, int ntiles) {
  __shared__ _Float16 bR[1024][8];
  __shared__ _Float16 bI[1024][8];
  __shared__ float xrT[4][16][65];
  const int tid = threadIdx.x;
  const int lane = tid & 63;
  const int wave = tid >> 6;
  for (int slot = tid; slot < 1024; slot += 256) {
    int g = slot >> 8;
    int c = (slot >> 6) & 3;
    int l = slot & 63;
    int col = g * 16 + (l & 15);
    int kb = c * 32 + ((l >> 4) << 3);
#pragma unroll
    for (int j = 0; j < 8; ++j) {
      int k = kb + j;
      float vr, vi;
      if (k < 64) {
        vr = UrT[k * 64 + col];
        vi = UiT[k * 64 + col];
      } else {
        vr = -UiT[(k - 64) * 64 + col];
        vi = UrT[(k - 64) * 64 + col];
      }
      bR[slot][j] = (_Float16)vr;
      bI[slot][j] = (_Float16)vi;
    }
  }
  __syncthreads();
  const int tile = blockIdx.x * 4 + wave;
  if (tile >= ntiles) return;
  const int base = tile << 4;
  for (int nn = 0; nn < 16; ++nn) {
    int node = min(base + nn, n - 1);
    float xv = x[(size_t)node * 64 + lane];
    float s1 = wsum64(xv);
    float s2 = wsum64(xv * xv);
    float mean = s1 * 0.015625f;
    float var = fmaf(-mean, mean, s2 * 0.015625f);
    xrT[wave][nn][lane] = (xv - mean) * rsqrtf(var + 1e-5f);
  }
  const int row = lane & 15;
  const int node = min(base + row, n - 1);
  const int kb = (lane >> 4) << 3;
  const _Float16* crp = (const _Float16*)(Crh + (size_t)node * 64);
  const _Float16* srp = (const _Float16*)(Srh + (size_t)node * 64);
  half8 a0 = *(const half8*)(crp + kb);
  half8 a1 = *(const half8*)(crp + 32 + kb);
  half8 a2 = *(const half8*)(srp + kb);
  half8 a3 = *(const half8*)(srp + 32 + kb);
  const size_t imag_off = (size_t)n * 64;
  const int rgrp = (lane >> 4) << 2;
#pragma unroll
  for (int g = 0; g < 4; ++g) {
    f32x4 accR = {0.f, 0.f, 0.f, 0.f};
    f32x4 accI = {0.f, 0.f, 0.f, 0.f};
    const int sb = g * 256 + lane;
    accR = __builtin_amdgcn_mfma_f32_16x16x32_f16(a0, *(const half8*)&bR[sb][0], accR, 0, 0, 0);
    accR = __builtin_amdgcn_mfma_f32_16x16x32_f16(a1, *(const half8*)&bR[sb + 64][0], accR, 0, 0, 0);
    accR = __builtin_amdgcn_mfma_f32_16x16x32_f16(a2, *(const half8*)&bR[sb + 128][0], accR, 0, 0, 0);
    accR = __builtin_amdgcn_mfma_f32_16x16x32_f16(a3, *(const half8*)&bR[sb + 192][0], accR, 0, 0, 0);
    accI = __builtin_amdgcn_mfma_f32_16x16x32_f16(a0, *(const half8*)&bI[sb][0], accI, 0, 0, 0);
    accI = __builtin_amdgcn_mfma_f32_16x16x32_f16(a1, *(const half8*)&bI[sb + 64][0], accI, 0, 0, 0);
    accI = __builtin_amdgcn_mfma_f32_16x16x32_f16(a2, *(const half8*)&bI[sb + 128][0], accI, 0, 0, 0);
    accI = __builtin_amdgcn_mfma_f32_16x16x32_f16(a3, *(const half8*)&bI[sb + 192][0], accI, 0, 0, 0);
    const int col = g * 16 + (lane & 15);
#pragma unroll
    for (int reg = 0; reg < 4; ++reg) {
      int r = base + rgrp + reg;
      if (r < n) {
        out[(size_t)r * 64 + col] = 0.5f * (accR[reg] + xrT[wave][rgrp + reg][col]);
        out[imag_off + (size_t)r * 64 + col] = 0.5f * accI[reg];
      }
    }
  }
}

extern "C" void kernel_launch(void* const* d_in, const int* in_sizes, int n_in,
                              void* d_out, int out_size, void* d_ws, size_t ws_size,
                              hipStream_t stream) {
  const float* x    = (const float*)d_in[0];
  const int*   ei   = (const int*)d_in[1];
  const float* ew   = (const float*)d_in[2];
  const float* Wr   = (const float*)d_in[3];
  const float* ln_g = (const float*)d_in[5];
  const float* ln_b = (const float*)d_in[6];
  const float* w1   = (const float*)d_in[7];
  const float* b1   = (const float*)d_in[8];
  const float* w2   = (const float*)d_in[9];
  const float* b2   = (const float*)d_in[10];
  const float* g1w  = (const float*)d_in[11];
  const float* g1b  = (const float*)d_in[12];
  const float* g2w  = (const float*)d_in[13];
  const float* g2b  = (const float*)d_in[14];
  const float* aw1  = (const float*)d_in[15];
  const float* ab1  = (const float*)d_in[16];
  const float* aw2  = (const float*)d_in[17];
  const float* ab2  = (const float*)d_in[18];
  const float* aw3  = (const float*)d_in[19];
  const float* ab3  = (const float*)d_in[20];
  const int n = in_sizes[0] / 64;
  const int e = in_sizes[1] / 2;
  float* out = (float*)d_out;

  float* ws = (float*)d_ws;
  float* Wg1  = ws;                           // 4096
  float* C0G1 = ws + 4096;                    // 64
  float* UrT  = ws + 4160;                    // 4096
  float* UiT  = ws + 8256;                    // 4096
  float* z2g  = ws + 12352;                   // 64
  float* pG   = ws + 12416;                   // 4096
  unsigned* AdjU = (unsigned*)(ws + 20544);   // 4096 u32
  unsigned* cnt = AdjU + 4096;                // n
  unsigned* off = cnt + n;                    // n+1
  unsigned* cur = off + n + 1;                // n
  size_t p0 = (20544 + 4096 + 3 * (size_t)n + 1 + 63) & ~(size_t)63;
  int* recS = (int*)(ws + p0);                // e
  size_t p1 = (p0 + (size_t)e + 63) & ~(size_t)63;
  float2* recCS = (float2*)(ws + p1);         // 2e
  size_t p2 = (p1 + 2 * (size_t)e + 63) & ~(size_t)63;
  ushort_t* R = (ushort_t*)(ws + p2);         // 64n f32-units
  size_t p3 = (p2 + 64 * (size_t)n + 63) & ~(size_t)63;
  __hip_bfloat16* Ad = (__hip_bfloat16*)(ws + p3);  // 16n
  size_t p4 = (p3 + 16 * (size_t)n + 63) & ~(size_t)63;
  __half* Crh = (__half*)(ws + p4);           // 32n
  size_t p5 = (p4 + 32 * (size_t)n + 63) & ~(size_t)63;
  __half* Srh = (__half*)(ws + p5);           // 32n

  const int ntiles = (n + 15) >> 4;
  const int fblocks = (ntiles + 3) >> 2;

  kInit<<<512, 256, 0, stream>>>(cnt, cur, n, AdjU, ln_g, ln_b, w1, b1, Wg1, C0G1);
  kNodeM<<<fblocks, 256, 0, stream>>>(x, Wr, Wg1, C0G1, w2, b2, R, Ad, Crh, Srh, n, ntiles);
  kCount<<<1024, 256, 0, stream>>>(ei, e, cnt, AdjU);
  kScan<<<1, 1024, 0, stream>>>(cnt, off, n);
  kPhaseFill<<<1024, 256, 0, stream>>>(ei, ew, e, R, Ad, C0G1, w2, b2, off, cur, recS, recCS);
  kScatter<<<2048, 256, 0, stream>>>(off, recS, recCS, R, Crh, Srh, n);
  kGcnMlp<<<1, 1024, 0, stream>>>(AdjU, g1w, g1b, g2w, g2b, aw1, ab1, aw2, ab2, z2g);
  kTanh<<<16, 256, 0, stream>>>(z2g, aw3, ab3, pG);
  kExpm<<<1, 1024, 0, stream>>>(pG, UrT, UiT);
  kFinalM<<<fblocks, 256, 0, stream>>>(x, Crh, Srh, UrT, UiT, out, n, ntiles);
}

// Round 18
// 308.935 us; speedup vs baseline: 5.6017x; 1.2118x over previous
//
#include <hip/hip_runtime.h>
#include <hip/hip_bf16.h>
#include <hip/hip_fp16.h>

#define MAXPH 0.78539816339744831f
typedef unsigned short ushort_t;
typedef _Float16 half8 __attribute__((ext_vector_type(8)));
typedef float f32x4 __attribute__((ext_vector_type(4)));

__device__ __forceinline__ float wsum64(float v) {
#pragma unroll
  for (int o = 32; o > 0; o >>= 1) v += __shfl_xor(v, o);
  return v;
}
__device__ __forceinline__ float bf2f(ushort_t u) {
  return __uint_as_float(((unsigned)u) << 16);
}

// ---- kCountPrep: blocks [0,1024) = per-dst histogram + AdjU; block 1024 = prep Wg1/C0G1
__global__ __launch_bounds__(256) void kCountPrep(
    const int* __restrict__ ei, int ne, unsigned* __restrict__ cnt,
    unsigned* __restrict__ AdjU,
    const float* __restrict__ ln_g, const float* __restrict__ ln_b,
    const float* __restrict__ w1, const float* __restrict__ b1,
    float* __restrict__ Wg1, float* __restrict__ C0G1) {
  if (blockIdx.x < 1024) {
    int t = blockIdx.x * 256 + threadIdx.x;
    int st = 1024 * 256;
    for (int e = t; e < ne; e += st) {
      int s = ei[e];
      int d = ei[ne + e];
      atomicAdd(&cnt[d], 1u);
      if ((unsigned)(s | d) < 64u) atomicAdd(&AdjU[d * 64 + s], 1u);
    }
  } else {
    int tt = threadIdx.x;
    for (int idx = tt; idx < 4096; idx += 256) {
      int j = idx >> 5;
      Wg1[idx] = ln_g[j] * w1[idx];
    }
    if (tt < 32) {
      float c0 = b1[tt], g1 = 0.f;
      for (int j = 0; j < 128; ++j) {
        float w = w1[j * 32 + tt];
        c0 = fmaf(ln_b[j], w, c0);
        g1 = fmaf(ln_g[j], w, g1);
      }
      C0G1[tt] = c0;
      C0G1[32 + tt] = g1;
    }
  }
}

// ---- kNodeM: MFMA node pipeline (writes R record, AdP record, self-loop Crh/Srh)
__global__ __launch_bounds__(256) void kNodeM(
    const float* __restrict__ x, const float* __restrict__ Wr,
    const float* __restrict__ Wg1, const float* __restrict__ C0G1,
    const float* __restrict__ w2, const float* __restrict__ b2,
    ushort_t* __restrict__ R, float* __restrict__ AdP,
    __half* __restrict__ Crh, __half* __restrict__ Srh, int n, int ntiles) {
  __shared__ _Float16 bWr[512][8];
  __shared__ _Float16 bAd[256][8];
  __shared__ _Float16 bAs[256][8];
  __shared__ _Float16 cmT[4][16][72];
  const int tid = threadIdx.x;
  const int lane = tid & 63;
  const int wave = tid >> 6;
  for (int slot = tid; slot < 512; slot += 256) {
    int g = slot >> 7;
    int c = (slot >> 6) & 1;
    int l = slot & 63;
    int col = g * 16 + (l & 15);
    int kb0 = c * 32 + ((l >> 4) << 3);
#pragma unroll
    for (int j = 0; j < 8; ++j) bWr[slot][j] = (_Float16)Wr[(kb0 + j) * 64 + col];
  }
  {
    int slot = tid;
    int g2 = slot >> 7;
    int c = (slot >> 6) & 1;
    int l = slot & 63;
    int col = g2 * 16 + (l & 15);
    int kb0 = c * 32 + ((l >> 4) << 3);
#pragma unroll
    for (int j = 0; j < 8; ++j) {
      bAd[slot][j] = (_Float16)Wg1[(kb0 + j) * 32 + col];
      bAs[slot][j] = (_Float16)Wg1[(64 + kb0 + j) * 32 + col];
    }
  }
  __syncthreads();
  const int tile = blockIdx.x * 4 + wave;
  if (tile >= ntiles) return;
  const int base = tile << 4;
  const int row = lane & 15;
  const int kb = (lane >> 4) << 3;
  const int nodeA = min(base + row, n - 1);
  const float* xp = x + (size_t)nodeA * 64;
  float xv[8], xh[8];
  *(float4*)&xv[0] = *(const float4*)(xp + kb);
  *(float4*)&xv[4] = *(const float4*)(xp + kb + 4);
  *(float4*)&xh[0] = *(const float4*)(xp + 32 + kb);
  *(float4*)&xh[4] = *(const float4*)(xp + 32 + kb + 4);
  float s1 = 0.f, s2 = 0.f;
#pragma unroll
  for (int j = 0; j < 8; ++j) {
    s1 += xv[j] + xh[j];
    s2 += xv[j] * xv[j] + xh[j] * xh[j];
  }
  s1 += __shfl_xor(s1, 16);
  s1 += __shfl_xor(s1, 32);
  s2 += __shfl_xor(s2, 16);
  s2 += __shfl_xor(s2, 32);
  float mean = s1 * 0.015625f;
  float var = fmaf(-mean, mean, s2 * 0.015625f);
  float rstd = rsqrtf(var + 1e-5f);
  half8 aLo, aHi;
#pragma unroll
  for (int j = 0; j < 8; ++j) {
    aLo[j] = (_Float16)((xv[j] - mean) * rstd);
    aHi[j] = (_Float16)((xh[j] - mean) * rstd);
  }
  f32x4 accH[4];
#pragma unroll
  for (int g = 0; g < 4; ++g) {
    f32x4 z4 = {0.f, 0.f, 0.f, 0.f};
    z4 = __builtin_amdgcn_mfma_f32_16x16x32_f16(aLo, *(const half8*)&bWr[g * 128 + lane][0], z4, 0, 0, 0);
    z4 = __builtin_amdgcn_mfma_f32_16x16x32_f16(aHi, *(const half8*)&bWr[g * 128 + 64 + lane][0], z4, 0, 0, 0);
    accH[g] = z4;
  }
  float cm[4][4];
  float p1[4] = {0.f, 0.f, 0.f, 0.f}, p2[4] = {0.f, 0.f, 0.f, 0.f};
#pragma unroll
  for (int g = 0; g < 4; ++g)
#pragma unroll
    for (int r = 0; r < 4; ++r) {
      float hv = accH[g][r];
      float m = fminf(sqrtf(fmaf(hv, hv, 1e-8f)), 10.f);
      cm[g][r] = m;
      p1[r] += m;
      p2[r] += m * m;
    }
#pragma unroll
  for (int o = 1; o <= 8; o <<= 1)
#pragma unroll
    for (int r = 0; r < 4; ++r) {
      p1[r] += __shfl_xor(p1[r], o);
      p2[r] += __shfl_xor(p2[r], o);
    }
  const int rgrp = (lane >> 4) << 2;
#pragma unroll
  for (int g = 0; g < 4; ++g)
#pragma unroll
    for (int r = 0; r < 4; ++r)
      cmT[wave][rgrp + r][g * 16 + (lane & 15)] = (_Float16)cm[g][r];
  half8 cLo = *(const half8*)&cmT[wave][row][kb];
  half8 cHi = *(const half8*)&cmT[wave][row][32 + kb];
  f32x4 accAd[2], accAs[2];
#pragma unroll
  for (int g2 = 0; g2 < 2; ++g2) {
    f32x4 z4 = {0.f, 0.f, 0.f, 0.f};
    z4 = __builtin_amdgcn_mfma_f32_16x16x32_f16(cLo, *(const half8*)&bAd[g2 * 128 + lane][0], z4, 0, 0, 0);
    z4 = __builtin_amdgcn_mfma_f32_16x16x32_f16(cHi, *(const half8*)&bAd[g2 * 128 + 64 + lane][0], z4, 0, 0, 0);
    accAd[g2] = z4;
    f32x4 w4 = {0.f, 0.f, 0.f, 0.f};
    w4 = __builtin_amdgcn_mfma_f32_16x16x32_f16(cLo, *(const half8*)&bAs[g2 * 128 + lane][0], w4, 0, 0, 0);
    w4 = __builtin_amdgcn_mfma_f32_16x16x32_f16(cHi, *(const half8*)&bAs[g2 * 128 + 64 + lane][0], w4, 0, 0, 0);
    accAs[g2] = w4;
  }
  const float b2r = b2[0];
  float c0v[2], g1v[2], w2v[2];
#pragma unroll
  for (int g2 = 0; g2 < 2; ++g2) {
    int k = g2 * 16 + (lane & 15);
    c0v[g2] = C0G1[k];
    g1v[g2] = C0G1[32 + k];
    w2v[g2] = w2[k];
  }
  float zp[4];
#pragma unroll
  for (int r = 0; r < 4; ++r) {
    float meanE = p1[r] * 0.015625f;
    float varE = fmaf(-meanE, meanE, p2[r] * 0.015625f);
    float rstdE = rsqrtf(varE + 1e-5f);
    float zz = 0.f;
#pragma unroll
    for (int g2 = 0; g2 < 2; ++g2) {
      float pre = fmaf(rstdE, fmaf(-meanE, g1v[g2], accAd[g2][r] + accAs[g2][r]), c0v[g2]);
      zz = fmaf(fmaxf(pre, 0.f), w2v[g2], zz);
    }
    zp[r] = zz;
  }
#pragma unroll
  for (int o = 1; o <= 8; o <<= 1)
#pragma unroll
    for (int r = 0; r < 4; ++r) zp[r] += __shfl_xor(zp[r], o);
  float csv[4], snv[4];
#pragma unroll
  for (int r = 0; r < 4; ++r) {
    float coup = 1.f / (1.f + expf(-(zp[r] + b2r)));
    float ph = fminf(0.3f * coup, MAXPH);
    sincosf(ph, &snv[r], &csv[r]);
  }
  const int colb = lane & 15;
#pragma unroll
  for (int r = 0; r < 4; ++r) {
    int node = base + rgrp + r;
    if (node >= n) break;
#pragma unroll
    for (int g = 0; g < 4; ++g) {
      int col = g * 16 + colb;
      float hv = accH[g][r];
      __hip_bfloat16 hb = __float2bfloat16(hv);
      R[(size_t)node * 128 + col] = *(ushort_t*)&hb;
      Crh[(size_t)node * 64 + col] = __float2half(hv * csv[r]);
      Srh[(size_t)node * 64 + col] = __float2half(hv * snv[r]);
    }
    ushort_t* ap = (ushort_t*)(AdP + (size_t)node * 64);
#pragma unroll
    for (int g2 = 0; g2 < 2; ++g2) {
      int col = g2 * 16 + colb;
      __hip_bfloat16 ab = __float2bfloat16(accAd[g2][r]);
      ap[col] = *(ushort_t*)&ab;
      __hip_bfloat16 sb2 = __float2bfloat16(accAs[g2][r]);
      R[(size_t)node * 128 + 64 + col] = *(ushort_t*)&sb2;
    }
    if (colb == 0) {
      float* sp = (float*)(R + (size_t)node * 128 + 96);
      sp[0] = p1[r];
      sp[1] = p2[r];
      float* dp = AdP + (size_t)node * 64;
      dp[16] = p1[r];
      dp[17] = p2[r];
    }
  }
}

// ---- kScanGcn: block 0 = prefix scan; block 1 = GCN x2 + pool + MLP -> z2
__global__ __launch_bounds__(1024) void kScanGcn(
    const unsigned* __restrict__ cnt, unsigned* __restrict__ off, int n,
    const unsigned* __restrict__ AdjU,
    const float* __restrict__ g1w, const float* __restrict__ g1b,
    const float* __restrict__ g2w, const float* __restrict__ g2b,
    const float* __restrict__ aw1, const float* __restrict__ ab1,
    const float* __restrict__ aw2, const float* __restrict__ ab2,
    float* __restrict__ z2g) {
  __shared__ float L0[64 * 65];
  __shared__ float L1[64 * 65];
  __shared__ float sdv[64], sts[64], sgp[64], sz1[64];
  __shared__ unsigned wsums[16];
  const int tid = threadIdx.x;
  if (blockIdx.x == 0) {
    const int C = (n + 1023) >> 10;
    const int lo = tid * C;
    const int hi = min(lo + C, n);
    unsigned s = 0;
    for (int i = lo; i < hi; ++i) s += cnt[i];
    unsigned v = s;
#pragma unroll
    for (int o = 1; o < 64; o <<= 1) {
      unsigned u = __shfl_up(v, o);
      if ((tid & 63) >= o) v += u;
    }
    if ((tid & 63) == 63) wsums[tid >> 6] = v;
    __syncthreads();
    if (tid == 0) {
      unsigned a = 0;
      for (int i = 0; i < 16; ++i) {
        unsigned c = wsums[i];
        wsums[i] = a;
        a += c;
      }
    }
    __syncthreads();
    unsigned run = wsums[tid >> 6] + (v - s);
    for (int i = lo; i < hi; ++i) {
      off[i] = run;
      run += cnt[i];
    }
    if (tid == 1023) off[n] = run;
    return;
  }
  // ---- gcn+mlp block
  for (int idx = tid; idx < 4096; idx += 1024) {
    int r = idx >> 6, c = idx & 63;
    L0[r * 65 + c] = (float)AdjU[idx];
  }
  __syncthreads();
  if (tid < 64) {
    float deg = 1.f;
    for (int s2 = 0; s2 < 64; ++s2) deg += L0[tid * 65 + s2];
    sdv[tid] = rsqrtf(deg);
  }
  __syncthreads();
  if (tid < 64) {
    float a = 0.f;
    for (int s2 = 0; s2 < 64; ++s2) a = fmaf(L0[tid * 65 + s2], sdv[s2], a);
    sts[tid] = a;
  }
  __syncthreads();
  for (int idx = tid; idx < 4096; idx += 1024) {
    int d = idx >> 6, kk = idx & 63;
    L1[d * 65 + kk] = fmaxf(fmaf(g1w[kk], fmaf(sts[d], sdv[d], sdv[d] * sdv[d]), g1b[kk]), 0.f);
  }
  __syncthreads();
  const int i = tid >> 4, j0 = (tid & 15) << 2;
  float xw[4] = {0, 0, 0, 0};
  for (int m = 0; m < 64; ++m) {
    float hm = L1[i * 65 + m];
    const float* w = g2w + m * 64 + j0;
#pragma unroll
    for (int q = 0; q < 4; ++q) xw[q] = fmaf(hm, w[q], xw[q]);
  }
  __syncthreads();
#pragma unroll
  for (int q = 0; q < 4; ++q) L1[i * 65 + j0 + q] = xw[q];
  __syncthreads();
  {
    float a[4] = {0, 0, 0, 0};
    for (int s2 = 0; s2 < 64; ++s2) {
      float w = L0[i * 65 + s2] * sdv[s2];
#pragma unroll
      for (int q = 0; q < 4; ++q) a[q] = fmaf(w, L1[s2 * 65 + j0 + q], a[q]);
    }
    float di = sdv[i], sc = di * di;
    float h2[4];
#pragma unroll
    for (int q = 0; q < 4; ++q)
      h2[q] = fmaf(a[q], di, fmaf(sc, L1[i * 65 + j0 + q], g2b[j0 + q]));
    __syncthreads();
#pragma unroll
    for (int q = 0; q < 4; ++q) L1[i * 65 + j0 + q] = h2[q];
  }
  __syncthreads();
  if (tid < 64) {
    float a = 0.f;
    for (int d = 0; d < 64; ++d) a += L1[d * 65 + tid];
    sgp[tid] = a * 0.015625f;
  }
  __syncthreads();
  if (tid < 64) {
    float a = ab1[tid];
    for (int m = 0; m < 64; ++m) a = fmaf(sgp[m], aw1[m * 64 + tid], a);
    sz1[tid] = fmaxf(a, 0.f);
  }
  __syncthreads();
  if (tid < 64) {
    float a = ab2[tid];
    for (int m = 0; m < 64; ++m) a = fmaf(sz1[m], aw2[m * 64 + tid], a);
    z2g[tid] = fmaxf(a, 0.f);
  }
}

// ---- kPhaseTanh: blocks [0,1024) = lane-per-edge phase -> {s, half2(cos,sin)} recs;
//                  blocks [1024,1040) = p = tanh(z2@aw3+ab3)
__global__ __launch_bounds__(256) void kPhaseTanh(
    const int* __restrict__ ei, const float* __restrict__ ew, int ne,
    const ushort_t* __restrict__ R, const float* __restrict__ AdP,
    const float* __restrict__ C0G1, const float* __restrict__ w2,
    const float* __restrict__ b2,
    const unsigned* __restrict__ off, unsigned* __restrict__ cur,
    int2* __restrict__ recSC,
    const float* __restrict__ z2g, const float* __restrict__ aw3,
    const float* __restrict__ ab3, float* __restrict__ pG) {
  if (blockIdx.x >= 1024) {
    int rc = (blockIdx.x - 1024) * 256 + threadIdx.x;
    float a = ab3[rc];
    for (int m = 0; m < 64; ++m) a = fmaf(z2g[m], aw3[m * 4096 + rc], a);
    pG[rc] = tanhf(a);
    return;
  }
  const float b2r = b2[0];
  int t = blockIdx.x * 256 + threadIdx.x;
  int st = 1024 * 256;
  for (int e = t; e < ne; e += st) {
    int s = ei[e];
    int d = ei[ne + e];
    const ushort_t* rs = R + (size_t)s * 128;
    const float* bp = AdP + (size_t)d * 64;
    float2 ps = *(const float2*)(rs + 96);
    float2 pd = *(const float2*)(bp + 16);
    float meanE = (ps.x + pd.x) * 0.0078125f;
    float varE = fmaf(-meanE, meanE, (ps.y + pd.y) * 0.0078125f);
    float rstdE = rsqrtf(varE + 1e-5f);
    const uint4* asq = (const uint4*)(rs + 64);
    const uint4* adq = (const uint4*)bp;
    float z = b2r;
#pragma unroll
    for (int q = 0; q < 4; ++q) {
      uint4 ua = adq[q];
      uint4 ub = asq[q];
      unsigned av[4] = {ua.x, ua.y, ua.z, ua.w};
      unsigned bv[4] = {ub.x, ub.y, ub.z, ub.w};
#pragma unroll
      for (int p = 0; p < 4; ++p) {
        int k0 = q * 8 + p * 2;
        float a0 = __uint_as_float(av[p] << 16);
        float a1 = __uint_as_float(av[p] & 0xFFFF0000u);
        float b0 = __uint_as_float(bv[p] << 16);
        float b1 = __uint_as_float(bv[p] & 0xFFFF0000u);
        float pre0 = fmaf(rstdE, fmaf(-meanE, C0G1[32 + k0], a0 + b0), C0G1[k0]);
        float pre1 = fmaf(rstdE, fmaf(-meanE, C0G1[32 + k0 + 1], a1 + b1), C0G1[k0 + 1]);
        z = fmaf(fmaxf(pre0, 0.f), w2[k0], z);
        z = fmaf(fmaxf(pre1, 0.f), w2[k0 + 1], z);
      }
    }
    float coup = 1.f / (1.f + expf(-z));
    float cw = fminf(fmaxf(ew[e], 0.1f), 2.f);
    float ph = fminf(0.3f * coup * cw, MAXPH);
    float sn, cs;
    sincosf(ph, &sn, &cs);
    unsigned p = atomicAdd(&cur[d], 1u);
    unsigned pos = off[d] + p;
    __half2 h2 = __floats2half2_rn(cs, sn);
    int2 rec;
    rec.x = s;
    rec.y = *(int*)&h2;
    recSC[pos] = rec;
  }
}

// ---- kScatter: wave-per-node register-accumulate gather
__global__ __launch_bounds__(256) void kScatter(
    const unsigned* __restrict__ off, const int2* __restrict__ recSC,
    const ushort_t* __restrict__ R,
    __half* __restrict__ Crh, __half* __restrict__ Srh, int n) {
  const int lane = threadIdx.x & 63;
  const int wid = (blockIdx.x * blockDim.x + threadIdx.x) >> 6;
  const int nw = (gridDim.x * blockDim.x) >> 6;
  for (int d = wid; d < n; d += nw) {
    unsigned u0 = off[d], u1 = off[d + 1];
    float accR = 0.f, accI = 0.f;
    unsigned j = u0;
    for (; j + 8 <= u1; j += 8) {
      int s8[8];
      float2 c8[8];
#pragma unroll
      for (int k = 0; k < 8; ++k) {
        int2 rec = recSC[j + k];
        s8[k] = rec.x;
        __half2 h2 = *(__half2*)&rec.y;
        c8[k] = __half22float2(h2);
      }
#pragma unroll
      for (int k = 0; k < 8; ++k) {
        float hv = bf2f(R[(size_t)s8[k] * 128 + lane]);
        accR = fmaf(hv, c8[k].x, accR);
        accI = fmaf(hv, c8[k].y, accI);
      }
    }
    for (; j < u1; ++j) {
      int2 rec = recSC[j];
      __half2 h2 = *(__half2*)&rec.y;
      float2 c = __half22float2(h2);
      float hv = bf2f(R[(size_t)rec.x * 128 + lane]);
      accR = fmaf(hv, c.x, accR);
      accI = fmaf(hv, c.y, accI);
    }
    size_t idx = (size_t)d * 64 + lane;
    Crh[idx] = __float2half(__half2float(Crh[idx]) + accR);
    Srh[idx] = __float2half(__half2float(Srh[idx]) + accI);
  }
}

// ---- kExpm: single block — B from p (padded LDS), dynamic scaling s, Taylor-6 + s squarings
__global__ __launch_bounds__(1024) void kExpm(const float* __restrict__ pG,
                                              float* __restrict__ UrT,
                                              float* __restrict__ UiT) {
  __shared__ float Br[64 * 65], Bi[64 * 65];
  __shared__ float Xr[64 * 68], Xi[64 * 68];
  __shared__ float rowsum[64];
  __shared__ int sSh;
  const int tid = threadIdx.x;
  const float SC0 = 0.05f;  // 0.1 * 0.5
  for (int idx = tid; idx < 4096; idx += 1024) {
    int r = idx >> 6, c = idx & 63;
    float pr = pG[r * 64 + c], pt = pG[c * 64 + r];
    Br[r * 65 + c] = (pr - pt) * SC0;
    Bi[r * 65 + c] = (pr + pt) * SC0;
  }
  __syncthreads();
  if (tid < 64) {
    float a = 0.f;
    for (int c = 0; c < 64; ++c) a += fabsf(Br[tid * 65 + c]) + fabsf(Bi[tid * 65 + c]);
    rowsum[tid] = a;
  }
  __syncthreads();
  if (tid == 0) {
    float m = 0.f;
    for (int i2 = 0; i2 < 64; ++i2) m = fmaxf(m, rowsum[i2]);
    int s = 0;
    while (m > 0.25f && s < 16) {
      m *= 0.5f;
      ++s;
    }
    sSh = s;
  }
  __syncthreads();
  const int sVal = sSh;
  const float scale = ldexpf(1.f, -sVal);
  for (int idx = tid; idx < 4096; idx += 1024) {
    int r = idx >> 6, c = idx & 63;
    float br = Br[r * 65 + c] * scale;
    float bi = Bi[r * 65 + c] * scale;
    Br[r * 65 + c] = br;
    Bi[r * 65 + c] = bi;
    Xr[r * 68 + c] = (r == c ? 1.f : 0.f) + br * (1.f / 6.f);
    Xi[r * 68 + c] = bi * (1.f / 6.f);
  }
  __syncthreads();
  const int i = tid >> 4, j0 = (tid & 15) << 2;
  for (int kk = 5; kk >= 1; --kk) {
    float ar[4] = {0, 0, 0, 0}, ai[4] = {0, 0, 0, 0};
    for (int m = 0; m < 64; ++m) {
      float br = Br[i * 65 + m], bi = Bi[i * 65 + m];
      float4 xr4 = *(const float4*)&Xr[m * 68 + j0];
      float4 xi4 = *(const float4*)&Xi[m * 68 + j0];
      float xr[4] = {xr4.x, xr4.y, xr4.z, xr4.w};
      float xi[4] = {xi4.x, xi4.y, xi4.z, xi4.w};
#pragma unroll
      for (int q = 0; q < 4; ++q) {
        ar[q] = fmaf(br, xr[q], fmaf(-bi, xi[q], ar[q]));
        ai[q] = fmaf(br, xi[q], fmaf(bi, xr[q], ai[q]));
      }
    }
    __syncthreads();
    float inv = 1.f / (float)kk;
#pragma unroll
    for (int q = 0; q < 4; ++q) {
      int c = j0 + q;
      Xr[i * 68 + c] = (i == c ? 1.f : 0.f) + ar[q] * inv;
      Xi[i * 68 + c] = ai[q] * inv;
    }
    __syncthreads();
  }
  for (int sq = 0; sq < sVal; ++sq) {
    float ar[4] = {0, 0, 0, 0}, ai[4] = {0, 0, 0, 0};
    for (int m = 0; m < 64; ++m) {
      float br = Xr[i * 68 + m], bi = Xi[i * 68 + m];
      float4 xr4 = *(const float4*)&Xr[m * 68 + j0];
      float4 xi4 = *(const float4*)&Xi[m * 68 + j0];
      float xr[4] = {xr4.x, xr4.y, xr4.z, xr4.w};
      float xi[4] = {xi4.x, xi4.y, xi4.z, xi4.w};
#pragma unroll
      for (int q = 0; q < 4; ++q) {
        ar[q] = fmaf(br, xr[q], fmaf(-bi, xi[q], ar[q]));
        ai[q] = fmaf(br, xi[q], fmaf(bi, xr[q], ai[q]));
      }
    }
    __syncthreads();
#pragma unroll
    for (int q = 0; q < 4; ++q) {
      Xr[i * 68 + j0 + q] = ar[q];
      Xi[i * 68 + j0 + q] = ai[q];
    }
    __syncthreads();
  }
  for (int idx = tid; idx < 4096; idx += 1024) {
    int a2 = idx >> 6, b2i = idx & 63;
    UrT[idx] = Xr[b2i * 68 + a2];
    UiT[idx] = Xi[b2i * 68 + a2];
  }
}

// ---- kFinalM: MFMA GEMM — OutR=[Cr|Sr]@[UrT;-UiT], OutI=[Cr|Sr]@[UiT;UrT]; +0.5*LN(x)
__global__ __launch_bounds__(256) void kFinalM(
    const float* __restrict__ x, const __half* __restrict__ Crh,
    const __half* __restrict__ Srh, const float* __restrict__ UrT,
    const float* __restrict__ UiT, float* __restrict__ out, int n, int ntiles) {
  __shared__ _Float16 bR[1024][8];
  __shared__ _Float16 bI[1024][8];
  __shared__ float xrT[4][16][65];
  const int tid = threadIdx.x;
  const int lane = tid & 63;
  const int wave = tid >> 6;
  for (int slot = tid; slot < 1024; slot += 256) {
    int g = slot >> 8;
    int c = (slot >> 6) & 3;
    int l = slot & 63;
    int col = g * 16 + (l & 15);
    int kb = c * 32 + ((l >> 4) << 3);
#pragma unroll
    for (int j = 0; j < 8; ++j) {
      int k = kb + j;
      float vr, vi;
      if (k < 64) {
        vr = UrT[k * 64 + col];
        vi = UiT[k * 64 + col];
      } else {
        vr = -UiT[(k - 64) * 64 + col];
        vi = UrT[(k - 64) * 64 + col];
      }
      bR[slot][j] = (_Float16)vr;
      bI[slot][j] = (_Float16)vi;
    }
  }
  __syncthreads();
  const int tile = blockIdx.x * 4 + wave;
  if (tile >= ntiles) return;
  const int base = tile << 4;
  for (int nn = 0; nn < 16; ++nn) {
    int node = min(base + nn, n - 1);
    float xv = x[(size_t)node * 64 + lane];
    float s1 = wsum64(xv);
    float s2 = wsum64(xv * xv);
    float mean = s1 * 0.015625f;
    float var = fmaf(-mean, mean, s2 * 0.015625f);
    xrT[wave][nn][lane] = (xv - mean) * rsqrtf(var + 1e-5f);
  }
  const int row = lane & 15;
  const int node = min(base + row, n - 1);
  const int kb = (lane >> 4) << 3;
  const _Float16* crp = (const _Float16*)(Crh + (size_t)node * 64);
  const _Float16* srp = (const _Float16*)(Srh + (size_t)node * 64);
  half8 a0 = *(const half8*)(crp + kb);
  half8 a1 = *(const half8*)(crp + 32 + kb);
  half8 a2 = *(const half8*)(srp + kb);
  half8 a3 = *(const half8*)(srp + 32 + kb);
  const size_t imag_off = (size_t)n * 64;
  const int rgrp = (lane >> 4) << 2;
#pragma unroll
  for (int g = 0; g < 4; ++g) {
    f32x4 accR = {0.f, 0.f, 0.f, 0.f};
    f32x4 accI = {0.f, 0.f, 0.f, 0.f};
    const int sb = g * 256 + lane;
    accR = __builtin_amdgcn_mfma_f32_16x16x32_f16(a0, *(const half8*)&bR[sb][0], accR, 0, 0, 0);
    accR = __builtin_amdgcn_mfma_f32_16x16x32_f16(a1, *(const half8*)&bR[sb + 64][0], accR, 0, 0, 0);
    accR = __builtin_amdgcn_mfma_f32_16x16x32_f16(a2, *(const half8*)&bR[sb + 128][0], accR, 0, 0, 0);
    accR = __builtin_amdgcn_mfma_f32_16x16x32_f16(a3, *(const half8*)&bR[sb + 192][0], accR, 0, 0, 0);
    accI = __builtin_amdgcn_mfma_f32_16x16x32_f16(a0, *(const half8*)&bI[sb][0], accI, 0, 0, 0);
    accI = __builtin_amdgcn_mfma_f32_16x16x32_f16(a1, *(const half8*)&bI[sb + 64][0], accI, 0, 0, 0);
    accI = __builtin_amdgcn_mfma_f32_16x16x32_f16(a2, *(const half8*)&bI[sb + 128][0], accI, 0, 0, 0);
    accI = __builtin_amdgcn_mfma_f32_16x16x32_f16(a3, *(const half8*)&bI[sb + 192][0], accI, 0, 0, 0);
    const int col = g * 16 + (lane & 15);
#pragma unroll
    for (int reg = 0; reg < 4; ++reg) {
      int r = base + rgrp + reg;
      if (r < n) {
        out[(size_t)r * 64 + col] = 0.5f * (accR[reg] + xrT[wave][rgrp + reg][col]);
        out[imag_off + (size_t)r * 64 + col] = 0.5f * accI[reg];
      }
    }
  }
}

extern "C" void kernel_launch(void* const* d_in, const int* in_sizes, int n_in,
                              void* d_out, int out_size, void* d_ws, size_t ws_size,
                              hipStream_t stream) {
  const float* x    = (const float*)d_in[0];
  const int*   ei   = (const int*)d_in[1];
  const float* ew   = (const float*)d_in[2];
  const float* Wr   = (const float*)d_in[3];
  const float* ln_g = (const float*)d_in[5];
  const float* ln_b = (const float*)d_in[6];
  const float* w1   = (const float*)d_in[7];
  const float* b1   = (const float*)d_in[8];
  const float* w2   = (const float*)d_in[9];
  const float* b2   = (const float*)d_in[10];
  const float* g1w  = (const float*)d_in[11];
  const float* g1b  = (const float*)d_in[12];
  const float* g2w  = (const float*)d_in[13];
  const float* g2b  = (const float*)d_in[14];
  const float* aw1  = (const float*)d_in[15];
  const float* ab1  = (const float*)d_in[16];
  const float* aw2  = (const float*)d_in[17];
  const float* ab2  = (const float*)d_in[18];
  const float* aw3  = (const float*)d_in[19];
  const float* ab3  = (const float*)d_in[20];
  const int n = in_sizes[0] / 64;
  const int e = in_sizes[1] / 2;
  float* out = (float*)d_out;

  float* ws = (float*)d_ws;
  float* Wg1  = ws;                           // 4096
  float* C0G1 = ws + 4096;                    // 64
  float* UrT  = ws + 4160;                    // 4096
  float* UiT  = ws + 8256;                    // 4096
  float* z2g  = ws + 12352;                   // 64
  float* pG   = ws + 12416;                   // 4096 -> ends 16512
  unsigned* AdjU = (unsigned*)(ws + 20544);   // 4096 u32 (contiguous zero region start)
  unsigned* cnt = AdjU + 4096;                // n
  unsigned* cur = cnt + n;                    // n
  unsigned* off = cur + n;                    // n+1 (written fully by scan)
  size_t p0 = (20544 + 4096 + 3 * (size_t)n + 1 + 63) & ~(size_t)63;
  int2* recSC = (int2*)(ws + p0);             // e int2 (= 2e floats)
  size_t p2 = (p0 + 2 * (size_t)e + 63) & ~(size_t)63;
  ushort_t* R = (ushort_t*)(ws + p2);         // 64n f32-units
  size_t p3 = (p2 + 64 * (size_t)n + 63) & ~(size_t)63;
  float* AdP = ws + p3;                       // 64n f32-units (Ad bf16[32] + S12 f32[2])
  size_t p4 = (p3 + 64 * (size_t)n + 63) & ~(size_t)63;
  __half* Crh = (__half*)(ws + p4);           // 32n
  size_t p5 = (p4 + 32 * (size_t)n + 63) & ~(size_t)63;
  __half* Srh = (__half*)(ws + p5);           // 32n

  const int ntiles = (n + 15) >> 4;
  const int fblocks = (ntiles + 3) >> 2;

  hipMemsetAsync(AdjU, 0, (4096 + 2 * (size_t)n) * 4, stream);
  kCountPrep<<<1025, 256, 0, stream>>>(ei, e, cnt, AdjU, ln_g, ln_b, w1, b1, Wg1, C0G1);
  kNodeM<<<fblocks, 256, 0, stream>>>(x, Wr, Wg1, C0G1, w2, b2, R, AdP, Crh, Srh, n, ntiles);
  kScanGcn<<<2, 1024, 0, stream>>>(cnt, off, n, AdjU, g1w, g1b, g2w, g2b, aw1, ab1, aw2, ab2, z2g);
  kPhaseTanh<<<1040, 256, 0, stream>>>(ei, ew, e, R, AdP, C0G1, w2, b2, off, cur, recSC,
                                       z2g, aw3, ab3, pG);
  kScatter<<<2048, 256, 0, stream>>>(off, recSC, R, Crh, Srh, n);
  kExpm<<<1, 1024, 0, stream>>>(pG, UrT, UiT);
  kFinalM<<<fblocks, 256, 0, stream>>>(x, Crh, Srh, UrT, UiT, out, n, ntiles);
}